// Round 7
// baseline (396.053 us; speedup 1.0000x reference)
//
#include <hip/hip_runtime.h>
#include <hip/hip_bf16.h>
#include <math.h>

// ---------------------------------------------------------------------------
// Problem constants
// ---------------------------------------------------------------------------
#define NM 100000
#define ND 20000
#define NA 50000
#define EDG 300000
#define CAP 32    // max in-degree slots per movie node (Poisson(6): P(>32)~1.6e-14)

// gemm_all v4: barrier-free streaming GEMM, B in LDS (bank-safe stride),
// 256-thr blocks, 2-deep register prefetch, 6 tiles/wave, single round.
#define NTM 6250   // NM/16
#define NTD 1250   // ND/16
#define NTA 3125   // NA/16
#define T_W 6      // tiles per wave
#define MB3 261    // ceil(6250/24)
#define DB3 53     // ceil(1250/24)
#define AB3 131    // ceil(3125/24)

typedef __attribute__((ext_vector_type(8))) short shortx8;
typedef __attribute__((ext_vector_type(4))) float floatx4;
typedef __attribute__((ext_vector_type(4))) int intx4;

__device__ __forceinline__ float bf2f(unsigned int u) {
    return __uint_as_float(u << 16);
}
__device__ __forceinline__ unsigned short f2bf(float f) {   // RNE (precomp only)
    unsigned int x = __float_as_uint(f);
    unsigned int r = x + 0x7fffu + ((x >> 16) & 1u);
    return (unsigned short)(r >> 16);
}
__device__ __forceinline__ unsigned short f2bf_fast(float f) {  // round-half-up
    return (unsigned short)((__float_as_uint(f) + 0x8000u) >> 16);
}
// pack 2 f32 -> dword [bf16(a) | bf16(b)<<16] : 2 add + 1 v_perm
__device__ __forceinline__ unsigned int pkbf2(float a, float b) {
    return __builtin_amdgcn_perm(__float_as_uint(b) + 0x8000u,
                                 __float_as_uint(a) + 0x8000u,
                                 0x07060302u);
}
// pack 8 f32 (two floatx4) -> shortx8 bf16, memory element order preserved
__device__ __forceinline__ shortx8 pack8(floatx4 a, floatx4 b) {
    intx4 r;
    r[0] = (int)pkbf2(a[0], a[1]);
    r[1] = (int)pkbf2(a[2], a[3]);
    r[2] = (int)pkbf2(b[0], b[1]);
    r[3] = (int)pkbf2(b[2], b[3]);
    return __builtin_bit_cast(shortx8, r);
}
__device__ __forceinline__ float gelu_exact(float x) {
    return 0.5f * x * (1.0f + erff(x * 0.70710678118654752f));
}

// ---------------------------------------------------------------------------
// Workspace layout (bytes)
// ---------------------------------------------------------------------------
static const size_t OFF_BT_Q      = 0;          // [2][144][128] bf16, HALF-MAJOR
static const size_t OFF_BT_KAMV_D = 73728;      // 256x128 bf16 (rows 0-127 ka, 128-255 mv)
static const size_t OFF_BT_KAMV_A = 139264;     // 256x128 bf16
static const size_t OFF_WKA_D     = 204800;     // 128x128 f32 TRANSPOSED [nc][e]
static const size_t OFF_WVM_D     = 270336;     // 128x128 f32 T
static const size_t OFF_WKA_A     = 335872;     // 128x128 f32 T
static const size_t OFF_WVM_A     = 401408;     // 128x128 f32 T
static const size_t OFF_BQ        = 466944;     // 144 f32
static const size_t OFF_B_KAMV_D  = 467520;     // 256 f32
static const size_t OFF_B_KAMV_A  = 468544;     // 256 f32
static const size_t OFF_BKA_D     = 469568;     // 128 f32
static const size_t OFF_BVM_D     = 470080;     // 128 f32
static const size_t OFF_BKA_A     = 470592;     // 128 f32
static const size_t OFF_BVM_A     = 471104;     // 128 f32
static const size_t OFF_WALS      = 471616;     // 128x8 f32 (g·Wa[0]@Wlin)
static const size_t OFF_BFIN      = 475712;     // 8 f32
static const size_t OFF_Q0        = 524288;     // NM*128 bf16   (25.6 MB)
static const size_t OFF_SKIPB     = 26124288;   // NM*8 f32      (3.2 MB)
static const size_t OFF_WQT       = 26124288;   // 128x128 f32 — overlaps SKIPB
static const size_t OFF_KAMV_D    = 29324288;   // ND*256 bf16   (10.24 MB)
static const size_t OFF_KAMV_A    = 39564288;   // NA*256 bf16   (25.6 MB)
static const size_t OFF_COUNTS    = 65164288;   // NM int32
static const size_t OFF_SLOTS     = 65564288;   // NM*CAP int32  (12.8 MB)
#define KAMV_A_DELTA 10240000   // OFF_KAMV_A - OFF_KAMV_D

// ---------------------------------------------------------------------------
// K0a: fold a_rel/m_rel/p·scale into Wk/Wv (stored TRANSPOSED); transpose Wq;
// epilogue tables; zero counts
// ---------------------------------------------------------------------------
__global__ __launch_bounds__(256) void precompA(
    const float* __restrict__ Wk, const float* __restrict__ bk,
    const float* __restrict__ Wv, const float* __restrict__ bv,
    const float* __restrict__ Wa, const float* __restrict__ ba,
    const float* __restrict__ Wlin, const float* __restrict__ blin,
    const float* __restrict__ a_rel, const float* __restrict__ m_rel,
    const float* __restrict__ p_rel, const float* __restrict__ skip,
    const float* __restrict__ bpre, const float* __restrict__ Wq,
    char* __restrict__ ws)
{
    int tid = blockIdx.x * 256 + threadIdx.x;
    if (tid < 65536) {
        int mat = tid >> 14, rem = tid & 16383;
        int e = rem >> 7, hf = rem & 127, h = hf >> 4, f = hf & 15;
        const float* Wsrc; const float* R; float sc; float* dst;
        if (mat == 0)      { Wsrc = Wk + 16384; R = a_rel;        sc = p_rel[h]     * 0.25f; dst = (float*)(ws + OFF_WKA_D); }
        else if (mat == 1) { Wsrc = Wv + 16384; R = m_rel;        sc = 1.0f;                 dst = (float*)(ws + OFF_WVM_D); }
        else if (mat == 2) { Wsrc = Wk + 32768; R = a_rel + 2048; sc = p_rel[8 + h] * 0.25f; dst = (float*)(ws + OFF_WKA_A); }
        else               { Wsrc = Wv + 32768; R = m_rel + 2048; sc = 1.0f;                 dst = (float*)(ws + OFF_WVM_A); }
        float s = 0.0f;
        for (int d = 0; d < 16; d++)
            s += Wsrc[e * 128 + h * 16 + d] * R[h * 256 + d * 16 + f];
        dst[hf * 128 + e] = s * sc;          // TRANSPOSED store
    } else if (tid < 66048) {
        int idx = tid - 65536;
        int mat = idx >> 7, hf = idx & 127, h = hf >> 4, f = hf & 15;
        const float* bsrc; const float* R; float sc; float* dst;
        if (mat == 0)      { bsrc = bk + 128; R = a_rel;        sc = p_rel[h]     * 0.25f; dst = (float*)(ws + OFF_BKA_D); }
        else if (mat == 1) { bsrc = bv + 128; R = m_rel;        sc = 1.0f;                 dst = (float*)(ws + OFF_BVM_D); }
        else if (mat == 2) { bsrc = bk + 256; R = a_rel + 2048; sc = p_rel[8 + h] * 0.25f; dst = (float*)(ws + OFF_BKA_A); }
        else               { bsrc = bv + 256; R = m_rel + 2048; sc = 1.0f;                 dst = (float*)(ws + OFF_BVM_A); }
        float s = 0.0f;
        for (int d = 0; d < 16; d++)
            s += bsrc[h * 16 + d] * R[h * 256 + d * 16 + f];
        dst[hf] = s * sc;
    } else if (tid < 67072) {
        // WaLs[j][c] = g * sum_o Wa[0][j][o] * Wlin[o][c]
        int idx = tid - 66048;
        int j = idx >> 3, c = idx & 7;
        float g = 1.0f / (1.0f + __expf(-skip[0]));
        float s = 0.0f;
        for (int o = 0; o < 128; o++)
            s += Wa[j * 128 + o] * Wlin[o * 8 + c];
        ((float*)(ws + OFF_WALS))[j * 8 + c] = g * s;
    } else if (tid < 67080) {
        int c = tid - 67072;
        float g = 1.0f / (1.0f + __expf(-skip[0]));
        float s1 = 0.0f, s2 = 0.0f;
        for (int o = 0; o < 128; o++) {
            s1 += ba[o]   * Wlin[o * 8 + c];
            s2 += bpre[o] * Wlin[o * 8 + c];
        }
        ((float*)(ws + OFF_BFIN))[c] = g * s1 + (1.0f - g) * s2 + blin[c];
    } else if (tid < 83464) {
        // WqT[n][e] = Wq[0][e][n]
        int i = tid - 67080;
        int n = i >> 7, e = i & 127;
        ((float*)(ws + OFF_WQT))[n * 128 + e] = Wq[e * 128 + n];
    } else if (tid < 83464 + NM) {
        ((int*)(ws + OFF_COUNTS))[tid - 83464] = 0;   // zero edge counters
    }
}

// ---------------------------------------------------------------------------
// contiguous-dot helper: 128-elem dot of two 16B-aligned f32 streams
// ---------------------------------------------------------------------------
__device__ __forceinline__ float dot128(const float* __restrict__ a,
                                        const float* __restrict__ b) {
    const floatx4* x = (const floatx4*)a;
    const floatx4* y = (const floatx4*)b;
    float s = 0.0f;
    #pragma unroll
    for (int i = 0; i < 32; i++) {
        floatx4 u = x[i], v = y[i];
        s += u[0] * v[0] + u[1] * v[1] + u[2] * v[2] + u[3] * v[3];
    }
    return s;
}

// ---------------------------------------------------------------------------
// K0b + edge scatter fused (independent work, block-range split).
// Blocks [0, 2344): scatter.  Blocks [2344, 2747): precompB.
// ---------------------------------------------------------------------------
__global__ __launch_bounds__(256) void prep_scat(
    const int* __restrict__ src_dm, const int* __restrict__ dst_dm,
    const int* __restrict__ src_am, const int* __restrict__ dst_am,
    const float* __restrict__ Wpre_m, const float* __restrict__ Wpre_d,
    const float* __restrict__ Wpre_a, const float* __restrict__ bpre,
    const float* __restrict__ bq, const float* __restrict__ Wlin,
    const float* __restrict__ skip,
    char* __restrict__ ws)
{
    if (blockIdx.x < 2344) {
        int t = blockIdx.x * 256 + threadIdx.x;
        if (t >= 2 * EDG) return;
        int src, dst, delta;
        if (t < EDG) { src = src_dm[t];       dst = dst_dm[t];       delta = 0; }
        else         { src = src_am[t - EDG]; dst = dst_am[t - EDG]; delta = KAMV_A_DELTA; }
        int* counts = (int*)(ws + OFF_COUNTS);
        int* slots  = (int*)(ws + OFF_SLOTS);
        int pos = atomicAdd(&counts[dst], 1);
        if (pos < CAP) slots[(size_t)dst * CAP + pos] = src * 512 + delta;
        return;
    }
    int tid = (blockIdx.x - 2344) * 256 + threadIdx.x;
    const float* WKA_D = (const float*)(ws + OFF_WKA_D);
    const float* WVM_D = (const float*)(ws + OFF_WVM_D);
    const float* WKA_A = (const float*)(ws + OFF_WKA_A);
    const float* WVM_A = (const float*)(ws + OFF_WVM_A);
    const float* WqT   = (const float*)(ws + OFF_WQT);

    if (tid < 36864) {
        int n = tid >> 8, c = tid & 255;
        float s = 0.0f;
        if (n < 128) {
            s = dot128(Wpre_m + c * 128, WqT + n * 128);
        } else if (n < 136) {
            int cc = n - 128;
            float g = 1.0f / (1.0f + __expf(-skip[0]));
            for (int e = 0; e < 128; e++)
                s += Wpre_m[c * 128 + e] * Wlin[e * 8 + cc];
            s *= (1.0f - g);
        }
        // HALF-MAJOR store: [c>>7][n][c&127]
        ((unsigned short*)(ws + OFF_BT_Q))[(c >> 7) * 18432 + n * 128 + (c & 127)] = f2bf(s);
    } else if (tid < 69632) {
        int idx = tid - 36864;
        int nrow = idx >> 7, c = idx & 127;
        const float* WfT = (nrow < 128) ? WKA_D : WVM_D;
        int nc = nrow & 127;
        float s = dot128(Wpre_d + c * 128, WfT + nc * 128);
        ((unsigned short*)(ws + OFF_BT_KAMV_D))[nrow * 128 + c] = f2bf(s);
    } else if (tid < 102400) {
        int idx = tid - 69632;
        int nrow = idx >> 7, c = idx & 127;
        const float* WfT = (nrow < 128) ? WKA_A : WVM_A;
        int nc = nrow & 127;
        float s = dot128(Wpre_a + c * 128, WfT + nc * 128);
        ((unsigned short*)(ws + OFF_BT_KAMV_A))[nrow * 128 + c] = f2bf(s);
    } else if (tid < 102544) {
        int n = tid - 102400;
        float s = 0.0f;
        if (n < 128) s = dot128(bpre, WqT + n * 128) + bq[n];
        ((float*)(ws + OFF_BQ))[n] = s;
    } else if (tid < 102800) {
        int nrow = tid - 102544;
        const float* WfT = (nrow < 128) ? WKA_D : WVM_D;
        const float* bf_ = (nrow < 128) ? (const float*)(ws + OFF_BKA_D) : (const float*)(ws + OFF_BVM_D);
        int nc = nrow & 127;
        ((float*)(ws + OFF_B_KAMV_D))[nrow] = dot128(bpre + 128, WfT + nc * 128) + bf_[nc];
    } else if (tid < 103056) {
        int nrow = tid - 102800;
        const float* WfT = (nrow < 128) ? WKA_A : WVM_A;
        const float* bf_ = (nrow < 128) ? (const float*)(ws + OFF_BKA_A) : (const float*)(ws + OFF_BVM_A);
        int nc = nrow & 127;
        ((float*)(ws + OFF_B_KAMV_A))[nrow] = dot128(bpre + 256, WfT + nc * 128) + bf_[nc];
    }
}

// ---------------------------------------------------------------------------
// gemm_all v4.
// B panels in LDS with bank-safe row stride (≡8 dwords mod 32): movie
// [144][272] shorts (K=256 contiguous per row), d/a [256][144] shorts.
// 256-thread blocks, launch_bounds(256,2) -> VGPR envelope ~256 (no cliff).
// Each wave streams 6 consecutive 16-row tiles; A staged in 2-deep register
// double-buffer st[2][] -> load-to-use distance = 2 iterations (~1000 cyc).
// No main-loop barriers. 445 blocks, 2/CU (LDS 78336B), single round.
// ---------------------------------------------------------------------------
#define MFMA16(a, b, c) __builtin_amdgcn_mfma_f32_16x16x32_bf16(a, b, c, 0, 0, 0)

__device__ __forceinline__ void stage_m(floatx4 (&buf)[16], const float* __restrict__ xm,
                                        int te, int low, int quad) {
    te = te < NTM ? te : NTM - 1;
    const float* Ap = xm + (size_t)(te * 16 + low) * 256 + quad * 8;
    #pragma unroll
    for (int ks = 0; ks < 8; ks++) {
        buf[2 * ks]     = *(const floatx4*)(Ap + ks * 32);
        buf[2 * ks + 1] = *(const floatx4*)(Ap + ks * 32 + 4);
    }
}

__device__ __forceinline__ void stage_k(floatx4 (&buf)[8], const float* __restrict__ A,
                                        int te, int ntt, int low, int quad) {
    te = te < ntt ? te : ntt - 1;
    const float* Ap = A + (size_t)(te * 16 + low) * 128 + quad * 8;
    #pragma unroll
    for (int ks = 0; ks < 4; ks++) {
        buf[2 * ks]     = *(const floatx4*)(Ap + ks * 32);
        buf[2 * ks + 1] = *(const floatx4*)(Ap + ks * 32 + 4);
    }
}

__global__ __launch_bounds__(256, 2) void gemm_all(
    const float* __restrict__ xm, const float* __restrict__ xd,
    const float* __restrict__ xa,
    const unsigned short* __restrict__ btq,   // [2][144][128] half-major
    const unsigned short* __restrict__ btd,   // [256][128]
    const unsigned short* __restrict__ bta,   // [256][128]
    const float* __restrict__ bq,
    const float* __restrict__ bbd, const float* __restrict__ bba,
    unsigned short* __restrict__ q0, float* __restrict__ skipb,
    unsigned short* __restrict__ outd, unsigned short* __restrict__ outa)
{
    __shared__ unsigned short b_lds[144 * 272];   // 78336 B; d/a view: [256][144]
    int tid = threadIdx.x;
    int w = tid >> 6, lane = tid & 63;
    int quad = lane >> 4, low = lane & 15;
    int bx = blockIdx.x;

    if (bx < MB3) {
        // ---------------- movie: q0 + skipb ----------------
        // fill b_lds[n][k] : row n (0..143), k global 0..255, stride 272 shorts
        #pragma unroll
        for (int it = 0; it < 18; it++) {
            int h = it / 9;
            int rem = (it % 9) * 256 + tid;       // 0..2303
            int n = rem >> 4, ch = rem & 15;
            *(intx4*)&b_lds[n * 272 + h * 128 + ch * 8] =
                *(const intx4*)&btq[(size_t)h * 18432 + n * 128 + ch * 8];
        }
        __syncthreads();
        float bqr[9];
        #pragma unroll
        for (int j = 0; j < 9; j++) bqr[j] = bq[j * 16 + low];

        int t0 = (bx * 4 + w) * T_W;
        floatx4 st[2][16];
        stage_m(st[0], xm, t0,     low, quad);
        stage_m(st[1], xm, t0 + 1, low, quad);
        #pragma unroll
        for (int i = 0; i < T_W; i++) {
            int t = t0 + i;
            shortx8 fa[8];
            #pragma unroll
            for (int ks = 0; ks < 8; ks++)
                fa[ks] = pack8(st[i & 1][2 * ks], st[i & 1][2 * ks + 1]);
            stage_m(st[i & 1], xm, t0 + i + 2, low, quad);   // 2-deep prefetch
            floatx4 acc[9] = {};
            #pragma unroll
            for (int ks = 0; ks < 8; ks++) {
                int kb = ks * 32 + quad * 8;
                #pragma unroll
                for (int j = 0; j < 9; j++) {
                    shortx8 b = *(const shortx8*)&b_lds[(j * 16 + low) * 272 + kb];
                    acc[j] = MFMA16(fa[ks], b, acc[j]);
                }
            }
            if (t < NTM) {
                int row0 = t * 16 + quad * 4;
                #pragma unroll
                for (int j = 0; j < 8; j++) {
                    int col = j * 16 + low;
                    #pragma unroll
                    for (int r = 0; r < 4; r++)
                        __builtin_nontemporal_store(f2bf_fast(acc[j][r] + bqr[j]),
                            &q0[(size_t)(row0 + r) * 128 + col]);
                }
                if (low < 8) {
                    #pragma unroll
                    for (int r = 0; r < 4; r++)
                        __builtin_nontemporal_store(acc[8][r] + bqr[8],
                            &skipb[(size_t)(row0 + r) * 8 + low]);
                }
            }
        }
    } else {
        // ---------------- director / actor: ka|mv ----------------
        const float* A; const unsigned short* BT; const float* bias;
        unsigned short* outb; int ntt, wid;
        if (bx < MB3 + DB3) { A = xd; BT = btd; bias = bbd; outb = outd; ntt = NTD; wid = (bx - MB3) * 4 + w; }
        else                { A = xa; BT = bta; bias = bba; outb = outa; ntt = NTA; wid = (bx - MB3 - DB3) * 4 + w; }
        #pragma unroll
        for (int it = 0; it < 16; it++) {
            int idx = it * 256 + tid;             // 0..4095
            int r = idx >> 4, ch = idx & 15;
            *(intx4*)&b_lds[r * 144 + ch * 8] =
                *(const intx4*)&BT[(size_t)r * 128 + ch * 8];
        }
        __syncthreads();
        float biasr[16];
        #pragma unroll
        for (int j = 0; j < 16; j++) biasr[j] = bias[j * 16 + low];

        int t0 = wid * T_W;
        floatx4 st[2][8];
        stage_k(st[0], A, t0,     ntt, low, quad);
        stage_k(st[1], A, t0 + 1, ntt, low, quad);
        #pragma unroll
        for (int i = 0; i < T_W; i++) {
            int t = t0 + i;
            shortx8 fa[4];
            #pragma unroll
            for (int ks = 0; ks < 4; ks++)
                fa[ks] = pack8(st[i & 1][2 * ks], st[i & 1][2 * ks + 1]);
            stage_k(st[i & 1], A, t0 + i + 2, ntt, low, quad);   // 2-deep prefetch
            floatx4 acc[16] = {};
            #pragma unroll
            for (int ks = 0; ks < 4; ks++) {
                int kb = ks * 32 + quad * 8;
                #pragma unroll
                for (int j = 0; j < 16; j++) {
                    shortx8 b = *(const shortx8*)&b_lds[(j * 16 + low) * 144 + kb];
                    acc[j] = MFMA16(fa[ks], b, acc[j]);
                }
            }
            if (t < ntt) {
                int row0 = t * 16 + quad * 4;
                #pragma unroll
                for (int j = 0; j < 16; j++) {
                    int col = j * 16 + low;
                    #pragma unroll
                    for (int r = 0; r < 4; r++)
                        outb[(size_t)(row0 + r) * 256 + col] = f2bf_fast(acc[j][r] + biasr[j]);
                }
            }
        }
    }
}

// ---------------------------------------------------------------------------
// Aggregation: 16 lanes/node, 4 nodes/wave, 1-deep edge prefetch.
// ---------------------------------------------------------------------------
__global__ __launch_bounds__(256) void agg_kernel(
    const unsigned short* __restrict__ q0,
    const char* __restrict__ kamv0,      // = ws + OFF_KAMV_D
    const int* __restrict__ counts, const int* __restrict__ slots,
    const float* __restrict__ skipb,
    const float* __restrict__ WaLs, const float* __restrict__ bfin,
    float* __restrict__ out)
{
    __shared__ float wals[1032];   // [c][j*16+L] transposed-interleaved + bfin
    for (int i = threadIdx.x; i < 1024; i += 256) {
        int c = i >> 7, rem = i & 127, j = rem >> 4, L = rem & 15;
        wals[i] = WaLs[(L * 8 + j) * 8 + c];
    }
    if (threadIdx.x < 8) wals[1024 + threadIdx.x] = bfin[threadIdx.x];
    __syncthreads();

    int lane = threadIdx.x & 63;
    int grp = lane >> 4;
    int L   = lane & 15;
    int n = blockIdx.x * 16 + (threadIdx.x >> 6) * 4 + grp;

    intx4 qv = *(const intx4*)(q0 + (size_t)n * 128 + L * 8);
    float qf[8];
    #pragma unroll
    for (int d = 0; d < 4; d++) {
        unsigned int u = (unsigned int)qv[d];
        qf[2 * d]     = __uint_as_float(u << 16);
        qf[2 * d + 1] = __uint_as_float(u & 0xffff0000u);
    }

    int cnt = counts[n];
    cnt = cnt < 0 ? 0 : (cnt > CAP ? CAP : cnt);
    int s0 = slots[(size_t)n * CAP + L];

    float acc[8] = {0, 0, 0, 0, 0, 0, 0, 0};
    float den = 0.0f;
    if (cnt > 0) {
        int off0 = __shfl(s0, lane & 48);
        const char* p = kamv0 + off0;
        intx4 ku = *(const intx4*)(p + L * 16);
        intx4 mu = *(const intx4*)(p + 256 + L * 16);
        for (int i = 0; i < cnt; i++) {
            int inext = (i + 1 < cnt) ? i + 1 : i;
            int offn = __shfl(s0, (lane & 48) + (inext & 15));
            if (__builtin_expect(inext >= 16, 0)) offn = slots[(size_t)n * CAP + inext];
            const char* pn = kamv0 + offn;
            intx4 kun = *(const intx4*)(pn + L * 16);
            intx4 mun = *(const intx4*)(pn + 256 + L * 16);

            float ph = 0.0f;
            #pragma unroll
            for (int d = 0; d < 4; d++) {
                unsigned int u = (unsigned int)ku[d];
                ph += qf[2 * d]     * __uint_as_float(u << 16);
                ph += qf[2 * d + 1] * __uint_as_float(u & 0xffff0000u);
            }
            float pf = ph + __shfl_xor(ph, 1);
            float wgt = __expf(fminf(pf, 60.0f));
            den += wgt;
            #pragma unroll
            for (int d = 0; d < 4; d++) {
                unsigned int u = (unsigned int)mu[d];
                acc[2 * d]     += wgt * __uint_as_float(u << 16);
                acc[2 * d + 1] += wgt * __uint_as_float(u & 0xffff0000u);
            }
            ku = kun; mu = mun;
        }
    }
    float inv = 1.0f / fmaxf(den, 1e-16f);

    float part[8] = {0, 0, 0, 0, 0, 0, 0, 0};
    #pragma unroll
    for (int j = 0; j < 8; j++) {
        float u = gelu_exact(acc[j] * inv);
        #pragma unroll
        for (int c = 0; c < 8; c++)
            part[c] += u * wals[c * 128 + j * 16 + L];
    }

    bool b0 = lane & 1, b1 = lane & 2, b2 = lane & 4;
    float t1[4], t2[2], t3;
    #pragma unroll
    for (int k = 0; k < 4; k++) {
        float send = b0 ? part[k] : part[4 + k];
        float got  = __shfl_xor(send, 1);
        t1[k] = (b0 ? part[4 + k] : part[k]) + got;
    }
    #pragma unroll
    for (int k = 0; k < 2; k++) {
        float send = b1 ? t1[k] : t1[2 + k];
        float got  = __shfl_xor(send, 2);
        t2[k] = (b1 ? t1[2 + k] : t1[k]) + got;
    }
    {
        float send = b2 ? t2[0] : t2[1];
        float got  = __shfl_xor(send, 4);
        t3 = (b2 ? t2[1] : t2[0]) + got;
    }
    t3 += __shfl_xor(t3, 8);
    if (L < 8) {
        int c = 4 * (L & 1) + 2 * ((L >> 1) & 1) + ((L >> 2) & 1);
        out[(size_t)n * 8 + c] = t3 + skipb[(size_t)n * 8 + c] + wals[1024 + c];
    }
}

// ---------------------------------------------------------------------------
// Host launch — 4 dispatches
// ---------------------------------------------------------------------------
extern "C" void kernel_launch(void* const* d_in, const int* in_sizes, int n_in,
                              void* d_out, int out_size, void* d_ws, size_t ws_size,
                              hipStream_t stream) {
    (void)in_sizes; (void)n_in; (void)out_size; (void)ws_size;
    const float* x_movie    = (const float*)d_in[0];
    const float* x_director = (const float*)d_in[1];
    const float* x_actor    = (const float*)d_in[2];
    const int* src_dm = (const int*)d_in[3];
    const int* dst_dm = (const int*)d_in[4];
    const int* src_am = (const int*)d_in[5];
    const int* dst_am = (const int*)d_in[6];
    const float* Wpre_m = (const float*)d_in[11];
    const float* Wpre_d = (const float*)d_in[12];
    const float* Wpre_a = (const float*)d_in[13];
    const float* bpre   = (const float*)d_in[14];
    const float* Wk     = (const float*)d_in[15];
    const float* bk     = (const float*)d_in[16];
    const float* Wq     = (const float*)d_in[17];
    const float* bq     = (const float*)d_in[18];
    const float* Wv     = (const float*)d_in[19];
    const float* bv     = (const float*)d_in[20];
    const float* a_rel  = (const float*)d_in[21];
    const float* m_rel  = (const float*)d_in[22];
    const float* p_rel  = (const float*)d_in[23];
    const float* skip   = (const float*)d_in[24];
    const float* Wa     = (const float*)d_in[25];
    const float* ba     = (const float*)d_in[26];
    const float* Wlin   = (const float*)d_in[27];
    const float* blin   = (const float*)d_in[28];

    char* ws = (char*)d_ws;
    float* out = (float*)d_out;

    precompA<<<(83464 + NM + 255) / 256, 256, 0, stream>>>(
        Wk, bk, Wv, bv, Wa, ba, Wlin, blin,
        a_rel, m_rel, p_rel, skip, bpre, Wq, ws);

    prep_scat<<<2344 + 403, 256, 0, stream>>>(
        src_dm, dst_dm, src_am, dst_am,
        Wpre_m, Wpre_d, Wpre_a, bpre, bq, Wlin, skip, ws);

    gemm_all<<<MB3 + DB3 + AB3, 256, 0, stream>>>(
        x_movie, x_director, x_actor,
        (const unsigned short*)(ws + OFF_BT_Q),
        (const unsigned short*)(ws + OFF_BT_KAMV_D),
        (const unsigned short*)(ws + OFF_BT_KAMV_A),
        (const float*)(ws + OFF_BQ),
        (const float*)(ws + OFF_B_KAMV_D), (const float*)(ws + OFF_B_KAMV_A),
        (unsigned short*)(ws + OFF_Q0), (float*)(ws + OFF_SKIPB),
        (unsigned short*)(ws + OFF_KAMV_D), (unsigned short*)(ws + OFF_KAMV_A));

    agg_kernel<<<NM / 16, 256, 0, stream>>>(
        (const unsigned short*)(ws + OFF_Q0),
        (const char*)(ws + OFF_KAMV_D),
        (const int*)(ws + OFF_COUNTS), (const int*)(ws + OFF_SLOTS),
        (const float*)(ws + OFF_SKIPB),
        (const float*)(ws + OFF_WALS), (const float*)(ws + OFF_BFIN), out);
}

// Round 9
// 378.885 us; speedup vs baseline: 1.0453x; 1.0453x over previous
//
#include <hip/hip_runtime.h>
#include <hip/hip_bf16.h>
#include <math.h>

// ---------------------------------------------------------------------------
// Problem constants
// ---------------------------------------------------------------------------
#define NM 100000
#define ND 20000
#define NA 50000
#define EDG 300000
#define CAP 32    // max in-degree slots per movie node (Poisson(6): P(>32)~1.6e-14)

// gemm_all v2 (measured 88us): barrier-free streaming GEMM, B resident in LDS.
// 16-row tiles per wave, 4 tiles per wave.
#define NTM 6250   // NM/16
#define NTD 1250   // ND/16
#define NTA 3125   // NA/16
#define MB  391    // ceil(6250/16) movie blocks (4 waves x 4 tiles)
#define DB  79     // ceil(1250/16)
#define AB  196    // ceil(3125/16)

typedef __attribute__((ext_vector_type(8))) short shortx8;
typedef __attribute__((ext_vector_type(4))) float floatx4;
typedef __attribute__((ext_vector_type(4))) int intx4;

__device__ __forceinline__ float bf2f(unsigned int u) {
    return __uint_as_float(u << 16);
}
__device__ __forceinline__ unsigned short f2bf(float f) {   // RNE (precomp only)
    unsigned int x = __float_as_uint(f);
    unsigned int r = x + 0x7fffu + ((x >> 16) & 1u);
    return (unsigned short)(r >> 16);
}
__device__ __forceinline__ unsigned short f2bf_fast(float f) {  // round-half-up
    return (unsigned short)((__float_as_uint(f) + 0x8000u) >> 16);
}
// pack 2 f32 -> dword [bf16(a) | bf16(b)<<16] : 2 add + 1 v_perm
__device__ __forceinline__ unsigned int pkbf2(float a, float b) {
    return __builtin_amdgcn_perm(__float_as_uint(b) + 0x8000u,
                                 __float_as_uint(a) + 0x8000u,
                                 0x07060302u);
}
// pack 8 f32 (two floatx4) -> shortx8 bf16, memory element order preserved
__device__ __forceinline__ shortx8 pack8(floatx4 a, floatx4 b) {
    intx4 r;
    r[0] = (int)pkbf2(a[0], a[1]);
    r[1] = (int)pkbf2(a[2], a[3]);
    r[2] = (int)pkbf2(b[0], b[1]);
    r[3] = (int)pkbf2(b[2], b[3]);
    return __builtin_bit_cast(shortx8, r);
}
__device__ __forceinline__ float gelu_exact(float x) {
    return 0.5f * x * (1.0f + erff(x * 0.70710678118654752f));
}

// ---------------------------------------------------------------------------
// Workspace layout (bytes)
// ---------------------------------------------------------------------------
static const size_t OFF_BT_Q      = 0;          // [2][144][128] bf16, HALF-MAJOR
static const size_t OFF_BT_KAMV_D = 73728;      // 256x128 bf16 (rows 0-127 ka, 128-255 mv)
static const size_t OFF_BT_KAMV_A = 139264;     // 256x128 bf16
static const size_t OFF_WKA_D     = 204800;     // 128x128 f32 TRANSPOSED [nc][e]
static const size_t OFF_WVM_D     = 270336;     // 128x128 f32 T
static const size_t OFF_WKA_A     = 335872;     // 128x128 f32 T
static const size_t OFF_WVM_A     = 401408;     // 128x128 f32 T
static const size_t OFF_BQ        = 466944;     // 144 f32
static const size_t OFF_B_KAMV_D  = 467520;     // 256 f32
static const size_t OFF_B_KAMV_A  = 468544;     // 256 f32
static const size_t OFF_BKA_D     = 469568;     // 128 f32
static const size_t OFF_BVM_D     = 470080;     // 128 f32
static const size_t OFF_BKA_A     = 470592;     // 128 f32
static const size_t OFF_BVM_A     = 471104;     // 128 f32
static const size_t OFF_WALS      = 471616;     // 128x8 f32 (g·Wa[0]@Wlin)
static const size_t OFF_BFIN      = 475712;     // 8 f32
static const size_t OFF_Q0        = 524288;     // NM*128 bf16   (25.6 MB)
static const size_t OFF_SKIPB     = 26124288;   // NM*8 f32      (3.2 MB)
static const size_t OFF_WQT       = 26124288;   // 128x128 f32 — overlaps SKIPB
static const size_t OFF_KAMV_D    = 29324288;   // ND*256 bf16   (10.24 MB)
static const size_t OFF_KAMV_A    = 39564288;   // NA*256 bf16   (25.6 MB)
static const size_t OFF_COUNTS    = 65164288;   // NM int32
static const size_t OFF_SLOTS     = 65564288;   // NM*CAP int32  (12.8 MB)
#define KAMV_A_DELTA 10240000   // OFF_KAMV_A - OFF_KAMV_D

// ---------------------------------------------------------------------------
// K0a: fold a_rel/m_rel/p·scale into Wk/Wv (stored TRANSPOSED); transpose Wq;
// epilogue tables; zero counts
// ---------------------------------------------------------------------------
__global__ __launch_bounds__(256) void precompA(
    const float* __restrict__ Wk, const float* __restrict__ bk,
    const float* __restrict__ Wv, const float* __restrict__ bv,
    const float* __restrict__ Wa, const float* __restrict__ ba,
    const float* __restrict__ Wlin, const float* __restrict__ blin,
    const float* __restrict__ a_rel, const float* __restrict__ m_rel,
    const float* __restrict__ p_rel, const float* __restrict__ skip,
    const float* __restrict__ bpre, const float* __restrict__ Wq,
    char* __restrict__ ws)
{
    int tid = blockIdx.x * 256 + threadIdx.x;
    if (tid < 65536) {
        int mat = tid >> 14, rem = tid & 16383;
        int e = rem >> 7, hf = rem & 127, h = hf >> 4, f = hf & 15;
        const float* Wsrc; const float* R; float sc; float* dst;
        if (mat == 0)      { Wsrc = Wk + 16384; R = a_rel;        sc = p_rel[h]     * 0.25f; dst = (float*)(ws + OFF_WKA_D); }
        else if (mat == 1) { Wsrc = Wv + 16384; R = m_rel;        sc = 1.0f;                 dst = (float*)(ws + OFF_WVM_D); }
        else if (mat == 2) { Wsrc = Wk + 32768; R = a_rel + 2048; sc = p_rel[8 + h] * 0.25f; dst = (float*)(ws + OFF_WKA_A); }
        else               { Wsrc = Wv + 32768; R = m_rel + 2048; sc = 1.0f;                 dst = (float*)(ws + OFF_WVM_A); }
        float s = 0.0f;
        for (int d = 0; d < 16; d++)
            s += Wsrc[e * 128 + h * 16 + d] * R[h * 256 + d * 16 + f];
        dst[hf * 128 + e] = s * sc;          // TRANSPOSED store
    } else if (tid < 66048) {
        int idx = tid - 65536;
        int mat = idx >> 7, hf = idx & 127, h = hf >> 4, f = hf & 15;
        const float* bsrc; const float* R; float sc; float* dst;
        if (mat == 0)      { bsrc = bk + 128; R = a_rel;        sc = p_rel[h]     * 0.25f; dst = (float*)(ws + OFF_BKA_D); }
        else if (mat == 1) { bsrc = bv + 128; R = m_rel;        sc = 1.0f;                 dst = (float*)(ws + OFF_BVM_D); }
        else if (mat == 2) { bsrc = bk + 256; R = a_rel + 2048; sc = p_rel[8 + h] * 0.25f; dst = (float*)(ws + OFF_BKA_A); }
        else               { bsrc = bv + 256; R = m_rel + 2048; sc = 1.0f;                 dst = (float*)(ws + OFF_BVM_A); }
        float s = 0.0f;
        for (int d = 0; d < 16; d++)
            s += bsrc[h * 16 + d] * R[h * 256 + d * 16 + f];
        dst[hf] = s * sc;
    } else if (tid < 67072) {
        // WaLs[j][c] = g * sum_o Wa[0][j][o] * Wlin[o][c]
        int idx = tid - 66048;
        int j = idx >> 3, c = idx & 7;
        float g = 1.0f / (1.0f + __expf(-skip[0]));
        float s = 0.0f;
        for (int o = 0; o < 128; o++)
            s += Wa[j * 128 + o] * Wlin[o * 8 + c];
        ((float*)(ws + OFF_WALS))[j * 8 + c] = g * s;
    } else if (tid < 67080) {
        int c = tid - 67072;
        float g = 1.0f / (1.0f + __expf(-skip[0]));
        float s1 = 0.0f, s2 = 0.0f;
        for (int o = 0; o < 128; o++) {
            s1 += ba[o]   * Wlin[o * 8 + c];
            s2 += bpre[o] * Wlin[o * 8 + c];
        }
        ((float*)(ws + OFF_BFIN))[c] = g * s1 + (1.0f - g) * s2 + blin[c];
    } else if (tid < 83464) {
        // WqT[n][e] = Wq[0][e][n]
        int i = tid - 67080;
        int n = i >> 7, e = i & 127;
        ((float*)(ws + OFF_WQT))[n * 128 + e] = Wq[e * 128 + n];
    } else if (tid < 83464 + NM) {
        ((int*)(ws + OFF_COUNTS))[tid - 83464] = 0;   // zero edge counters
    }
}

// ---------------------------------------------------------------------------
// contiguous-dot helper: 128-elem dot of two 16B-aligned f32 streams
// ---------------------------------------------------------------------------
__device__ __forceinline__ float dot128(const float* __restrict__ a,
                                        const float* __restrict__ b) {
    const floatx4* x = (const floatx4*)a;
    const floatx4* y = (const floatx4*)b;
    float s = 0.0f;
    #pragma unroll
    for (int i = 0; i < 32; i++) {
        floatx4 u = x[i], v = y[i];
        s += u[0] * v[0] + u[1] * v[1] + u[2] * v[2] + u[3] * v[3];
    }
    return s;
}

// ---------------------------------------------------------------------------
// K0b + edge scatter fused (independent work, block-range split).
// Blocks [0, 2344): scatter.  Blocks [2344, 2747): precompB.
// ---------------------------------------------------------------------------
__global__ __launch_bounds__(256) void prep_scat(
    const int* __restrict__ src_dm, const int* __restrict__ dst_dm,
    const int* __restrict__ src_am, const int* __restrict__ dst_am,
    const float* __restrict__ Wpre_m, const float* __restrict__ Wpre_d,
    const float* __restrict__ Wpre_a, const float* __restrict__ bpre,
    const float* __restrict__ bq, const float* __restrict__ Wlin,
    const float* __restrict__ skip,
    char* __restrict__ ws)
{
    if (blockIdx.x < 2344) {
        int t = blockIdx.x * 256 + threadIdx.x;
        if (t >= 2 * EDG) return;
        int src, dst, delta;
        if (t < EDG) { src = src_dm[t];       dst = dst_dm[t];       delta = 0; }
        else         { src = src_am[t - EDG]; dst = dst_am[t - EDG]; delta = KAMV_A_DELTA; }
        int* counts = (int*)(ws + OFF_COUNTS);
        int* slots  = (int*)(ws + OFF_SLOTS);
        int pos = atomicAdd(&counts[dst], 1);
        if (pos < CAP) slots[(size_t)dst * CAP + pos] = src * 512 + delta;
        return;
    }
    int tid = (blockIdx.x - 2344) * 256 + threadIdx.x;
    const float* WKA_D = (const float*)(ws + OFF_WKA_D);
    const float* WVM_D = (const float*)(ws + OFF_WVM_D);
    const float* WKA_A = (const float*)(ws + OFF_WKA_A);
    const float* WVM_A = (const float*)(ws + OFF_WVM_A);
    const float* WqT   = (const float*)(ws + OFF_WQT);

    if (tid < 36864) {
        int n = tid >> 8, c = tid & 255;
        float s = 0.0f;
        if (n < 128) {
            s = dot128(Wpre_m + c * 128, WqT + n * 128);
        } else if (n < 136) {
            int cc = n - 128;
            float g = 1.0f / (1.0f + __expf(-skip[0]));
            for (int e = 0; e < 128; e++)
                s += Wpre_m[c * 128 + e] * Wlin[e * 8 + cc];
            s *= (1.0f - g);
        }
        // HALF-MAJOR store: [c>>7][n][c&127]
        ((unsigned short*)(ws + OFF_BT_Q))[(c >> 7) * 18432 + n * 128 + (c & 127)] = f2bf(s);
    } else if (tid < 69632) {
        int idx = tid - 36864;
        int nrow = idx >> 7, c = idx & 127;
        const float* WfT = (nrow < 128) ? WKA_D : WVM_D;
        int nc = nrow & 127;
        float s = dot128(Wpre_d + c * 128, WfT + nc * 128);
        ((unsigned short*)(ws + OFF_BT_KAMV_D))[nrow * 128 + c] = f2bf(s);
    } else if (tid < 102400) {
        int idx = tid - 69632;
        int nrow = idx >> 7, c = idx & 127;
        const float* WfT = (nrow < 128) ? WKA_A : WVM_A;
        int nc = nrow & 127;
        float s = dot128(Wpre_a + c * 128, WfT + nc * 128);
        ((unsigned short*)(ws + OFF_BT_KAMV_A))[nrow * 128 + c] = f2bf(s);
    } else if (tid < 102544) {
        int n = tid - 102400;
        float s = 0.0f;
        if (n < 128) s = dot128(bpre, WqT + n * 128) + bq[n];
        ((float*)(ws + OFF_BQ))[n] = s;
    } else if (tid < 102800) {
        int nrow = tid - 102544;
        const float* WfT = (nrow < 128) ? WKA_D : WVM_D;
        const float* bf_ = (nrow < 128) ? (const float*)(ws + OFF_BKA_D) : (const float*)(ws + OFF_BVM_D);
        int nc = nrow & 127;
        ((float*)(ws + OFF_B_KAMV_D))[nrow] = dot128(bpre + 128, WfT + nc * 128) + bf_[nc];
    } else if (tid < 103056) {
        int nrow = tid - 102800;
        const float* WfT = (nrow < 128) ? WKA_A : WVM_A;
        const float* bf_ = (nrow < 128) ? (const float*)(ws + OFF_BKA_A) : (const float*)(ws + OFF_BVM_A);
        int nc = nrow & 127;
        ((float*)(ws + OFF_B_KAMV_A))[nrow] = dot128(bpre + 256, WfT + nc * 128) + bf_[nc];
    }
}

// ---------------------------------------------------------------------------
// gemm_all v2 (measured 88us): barrier-free streaming GEMM.
// B (weights, 69-78 KB) loaded into LDS ONCE per block, one sync, then each
// wave independently streams its own 16-row A tiles global->reg->bf16->MFMA.
// No __syncthreads in the main loop; 1-deep register prefetch hides HBM.
// LDS 78336 B -> 2 blocks/CU, 8 waves/CU.
// ---------------------------------------------------------------------------
#define MFMA16(a, b, c) __builtin_amdgcn_mfma_f32_16x16x32_bf16(a, b, c, 0, 0, 0)

__global__ __launch_bounds__(256, 2) void gemm_all(
    const float* __restrict__ xm, const float* __restrict__ xd,
    const float* __restrict__ xa,
    const unsigned short* __restrict__ btq,   // [2][144][128] half-major
    const unsigned short* __restrict__ btd,   // [256][128]
    const unsigned short* __restrict__ bta,   // [256][128]
    const float* __restrict__ bq,
    const float* __restrict__ bbd, const float* __restrict__ bba,
    unsigned short* __restrict__ q0, float* __restrict__ skipb,
    unsigned short* __restrict__ outd, unsigned short* __restrict__ outa)
{
    __shared__ unsigned short b_lds[288 * 136];   // 78336 B (d/a use first 256 rows)
    int tid = threadIdx.x;
    int w = tid >> 6, lane = tid & 63;
    int quad = lane >> 4, low = lane & 15;
    int bx = blockIdx.x;

    if (bx < MB) {
        // ---------------- movie: q0 + skipb ----------------
        #pragma unroll
        for (int it = 0; it < 18; it++) {
            int idx = it * 256 + tid, r = idx >> 4, ch = idx & 15;
            *(intx4*)&b_lds[r * 136 + ch * 8] =
                *(const intx4*)&btq[(size_t)r * 128 + ch * 8];
        }
        __syncthreads();
        float bqr[9];
        #pragma unroll
        for (int j = 0; j < 9; j++) bqr[j] = bq[j * 16 + low];

        int t0 = (bx * 4 + w) * 4;
        floatx4 st[16];
        {   // stage first tile
            int te = t0 < NTM ? t0 : NTM - 1;
            const float* Ap = xm + (size_t)(te * 16 + low) * 256 + quad * 8;
            #pragma unroll
            for (int ks = 0; ks < 8; ks++) {
                st[2 * ks]     = *(const floatx4*)(Ap + ks * 32);
                st[2 * ks + 1] = *(const floatx4*)(Ap + ks * 32 + 4);
            }
        }
        #pragma unroll
        for (int i = 0; i < 4; i++) {
            int t = t0 + i;
            shortx8 fa[8];
            #pragma unroll
            for (int ks = 0; ks < 8; ks++) fa[ks] = pack8(st[2 * ks], st[2 * ks + 1]);
            {   // prefetch next tile (clamped; in flight during MFMAs)
                int tn = t + 1 < NTM ? t + 1 : NTM - 1;
                const float* Ap = xm + (size_t)(tn * 16 + low) * 256 + quad * 8;
                #pragma unroll
                for (int ks = 0; ks < 8; ks++) {
                    st[2 * ks]     = *(const floatx4*)(Ap + ks * 32);
                    st[2 * ks + 1] = *(const floatx4*)(Ap + ks * 32 + 4);
                }
            }
            floatx4 acc[9] = {};
            #pragma unroll
            for (int ks = 0; ks < 8; ks++) {
                int rb = (ks >> 2) * 19584 + low * 136 + (ks & 3) * 32 + quad * 8;
                #pragma unroll
                for (int j = 0; j < 9; j++) {
                    shortx8 b = *(const shortx8*)&b_lds[rb + j * 2176];
                    acc[j] = MFMA16(fa[ks], b, acc[j]);
                }
            }
            if (t < NTM) {
                int row0 = t * 16 + quad * 4;
                #pragma unroll
                for (int j = 0; j < 8; j++) {
                    int col = j * 16 + low;
                    #pragma unroll
                    for (int r = 0; r < 4; r++)
                        q0[(size_t)(row0 + r) * 128 + col] = f2bf_fast(acc[j][r] + bqr[j]);
                }
                if (low < 8) {
                    #pragma unroll
                    for (int r = 0; r < 4; r++)
                        skipb[(size_t)(row0 + r) * 8 + low] = acc[8][r] + bqr[8];
                }
            }
        }
    } else {
        // ---------------- director / actor: ka|mv ----------------
        const float* A; const unsigned short* BT; const float* bias;
        unsigned short* outb; int ntt, wid;
        if (bx < MB + DB) { A = xd; BT = btd; bias = bbd; outb = outd; ntt = NTD; wid = (bx - MB) * 4 + w; }
        else              { A = xa; BT = bta; bias = bba; outb = outa; ntt = NTA; wid = (bx - MB - DB) * 4 + w; }
        #pragma unroll
        for (int it = 0; it < 16; it++) {
            int idx = it * 256 + tid, r = idx >> 4, ch = idx & 15;
            *(intx4*)&b_lds[r * 136 + ch * 8] =
                *(const intx4*)&BT[(size_t)r * 128 + ch * 8];
        }
        __syncthreads();
        float biasr[16];
        #pragma unroll
        for (int j = 0; j < 16; j++) biasr[j] = bias[j * 16 + low];

        int t0 = wid * 4;
        floatx4 st[8];
        {
            int te = t0 < ntt ? t0 : ntt - 1;
            const float* Ap = A + (size_t)(te * 16 + low) * 128 + quad * 8;
            #pragma unroll
            for (int ks = 0; ks < 4; ks++) {
                st[2 * ks]     = *(const floatx4*)(Ap + ks * 32);
                st[2 * ks + 1] = *(const floatx4*)(Ap + ks * 32 + 4);
            }
        }
        #pragma unroll
        for (int i = 0; i < 4; i++) {
            int t = t0 + i;
            shortx8 fa[4];
            #pragma unroll
            for (int ks = 0; ks < 4; ks++) fa[ks] = pack8(st[2 * ks], st[2 * ks + 1]);
            {
                int tn = t + 1 < ntt ? t + 1 : ntt - 1;
                const float* Ap = A + (size_t)(tn * 16 + low) * 128 + quad * 8;
                #pragma unroll
                for (int ks = 0; ks < 4; ks++) {
                    st[2 * ks]     = *(const floatx4*)(Ap + ks * 32);
                    st[2 * ks + 1] = *(const floatx4*)(Ap + ks * 32 + 4);
                }
            }
            floatx4 acc[16] = {};
            #pragma unroll
            for (int ks = 0; ks < 4; ks++) {
                int rb = low * 136 + ks * 32 + quad * 8;
                #pragma unroll
                for (int j = 0; j < 16; j++) {
                    shortx8 b = *(const shortx8*)&b_lds[rb + j * 2176];
                    acc[j] = MFMA16(fa[ks], b, acc[j]);
                }
            }
            if (t < ntt) {
                int row0 = t * 16 + quad * 4;
                #pragma unroll
                for (int j = 0; j < 16; j++) {
                    int col = j * 16 + low;
                    #pragma unroll
                    for (int r = 0; r < 4; r++)
                        outb[(size_t)(row0 + r) * 256 + col] = f2bf_fast(acc[j][r] + biasr[j]);
                }
            }
        }
    }
}

// ---------------------------------------------------------------------------
// Aggregation: 16 lanes/node, 4 nodes/wave, 2-deep edge prefetch (new).
// Edge i+2's 512B gather is issued while edge i is consumed -> load-to-use
// distance = 2 iterations, hiding the L2/L3 gather latency that previously
// stalled each edge.
// ---------------------------------------------------------------------------
__global__ __launch_bounds__(256) void agg_kernel(
    const unsigned short* __restrict__ q0,
    const char* __restrict__ kamv0,      // = ws + OFF_KAMV_D
    const int* __restrict__ counts, const int* __restrict__ slots,
    const float* __restrict__ skipb,
    const float* __restrict__ WaLs, const float* __restrict__ bfin,
    float* __restrict__ out)
{
    __shared__ float wals[1032];   // [c][j*16+L] transposed-interleaved + bfin
    for (int i = threadIdx.x; i < 1024; i += 256) {
        int c = i >> 7, rem = i & 127, j = rem >> 4, L = rem & 15;
        wals[i] = WaLs[(L * 8 + j) * 8 + c];
    }
    if (threadIdx.x < 8) wals[1024 + threadIdx.x] = bfin[threadIdx.x];
    __syncthreads();

    int lane = threadIdx.x & 63;
    int grp = lane >> 4;
    int L   = lane & 15;
    int n = blockIdx.x * 16 + (threadIdx.x >> 6) * 4 + grp;

    intx4 qv = *(const intx4*)(q0 + (size_t)n * 128 + L * 8);
    float qf[8];
    #pragma unroll
    for (int d = 0; d < 4; d++) {
        unsigned int u = (unsigned int)qv[d];
        qf[2 * d]     = __uint_as_float(u << 16);
        qf[2 * d + 1] = __uint_as_float(u & 0xffff0000u);
    }

    int cnt = counts[n];
    cnt = cnt < 0 ? 0 : (cnt > CAP ? CAP : cnt);
    int s0 = slots[(size_t)n * CAP + L];

    float acc[8] = {0, 0, 0, 0, 0, 0, 0, 0};
    float den = 0.0f;
    if (cnt > 0) {
        // edge 0
        int off0 = __shfl(s0, lane & 48);
        const char* p0 = kamv0 + off0;
        intx4 ku = *(const intx4*)(p0 + L * 16);
        intx4 mu = *(const intx4*)(p0 + 256 + L * 16);
        // edge 1 (clamped)
        int e1 = 1 < cnt ? 1 : cnt - 1;
        int off1 = __shfl(s0, (lane & 48) + (e1 & 15));
        if (__builtin_expect(e1 >= 16, 0)) off1 = slots[(size_t)n * CAP + e1];
        const char* p1 = kamv0 + off1;
        intx4 kun = *(const intx4*)(p1 + L * 16);
        intx4 mun = *(const intx4*)(p1 + 256 + L * 16);

        for (int i = 0; i < cnt; i++) {
            // issue edge i+2 (clamped) -> consumed two iterations later
            int e2 = (i + 2 < cnt) ? i + 2 : cnt - 1;
            int off2 = __shfl(s0, (lane & 48) + (e2 & 15));
            if (__builtin_expect(e2 >= 16, 0)) off2 = slots[(size_t)n * CAP + e2];
            const char* p2 = kamv0 + off2;
            intx4 ku2 = *(const intx4*)(p2 + L * 16);
            intx4 mu2 = *(const intx4*)(p2 + 256 + L * 16);

            float ph = 0.0f;
            #pragma unroll
            for (int d = 0; d < 4; d++) {
                unsigned int u = (unsigned int)ku[d];
                ph += qf[2 * d]     * __uint_as_float(u << 16);
                ph += qf[2 * d + 1] * __uint_as_float(u & 0xffff0000u);
            }
            float pf = ph + __shfl_xor(ph, 1);
            float wgt = __expf(fminf(pf, 60.0f));
            den += wgt;
            #pragma unroll
            for (int d = 0; d < 4; d++) {
                unsigned int u = (unsigned int)mu[d];
                acc[2 * d]     += wgt * __uint_as_float(u << 16);
                acc[2 * d + 1] += wgt * __uint_as_float(u & 0xffff0000u);
            }
            ku = kun; mu = mun; kun = ku2; mun = mu2;
        }
    }
    float inv = 1.0f / fmaxf(den, 1e-16f);

    float part[8] = {0, 0, 0, 0, 0, 0, 0, 0};
    #pragma unroll
    for (int j = 0; j < 8; j++) {
        float u = gelu_exact(acc[j] * inv);
        #pragma unroll
        for (int c = 0; c < 8; c++)
            part[c] += u * wals[c * 128 + j * 16 + L];
    }

    bool b0 = lane & 1, b1 = lane & 2, b2 = lane & 4;
    float t1[4], t2[2], t3;
    #pragma unroll
    for (int k = 0; k < 4; k++) {
        float send = b0 ? part[k] : part[4 + k];
        float got  = __shfl_xor(send, 1);
        t1[k] = (b0 ? part[4 + k] : part[k]) + got;
    }
    #pragma unroll
    for (int k = 0; k < 2; k++) {
        float send = b1 ? t1[k] : t1[2 + k];
        float got  = __shfl_xor(send, 2);
        t2[k] = (b1 ? t1[2 + k] : t1[k]) + got;
    }
    {
        float send = b2 ? t2[0] : t2[1];
        float got  = __shfl_xor(send, 4);
        t3 = (b2 ? t2[1] : t2[0]) + got;
    }
    t3 += __shfl_xor(t3, 8);
    if (L < 8) {
        int c = 4 * (L & 1) + 2 * ((L >> 1) & 1) + ((L >> 2) & 1);
        out[(size_t)n * 8 + c] = t3 + skipb[(size_t)n * 8 + c] + wals[1024 + c];
    }
}

// ---------------------------------------------------------------------------
// Host launch — 4 dispatches
// ---------------------------------------------------------------------------
extern "C" void kernel_launch(void* const* d_in, const int* in_sizes, int n_in,
                              void* d_out, int out_size, void* d_ws, size_t ws_size,
                              hipStream_t stream) {
    (void)in_sizes; (void)n_in; (void)out_size; (void)ws_size;
    const float* x_movie    = (const float*)d_in[0];
    const float* x_director = (const float*)d_in[1];
    const float* x_actor    = (const float*)d_in[2];
    const int* src_dm = (const int*)d_in[3];
    const int* dst_dm = (const int*)d_in[4];
    const int* src_am = (const int*)d_in[5];
    const int* dst_am = (const int*)d_in[6];
    const float* Wpre_m = (const float*)d_in[11];
    const float* Wpre_d = (const float*)d_in[12];
    const float* Wpre_a = (const float*)d_in[13];
    const float* bpre   = (const float*)d_in[14];
    const float* Wk     = (const float*)d_in[15];
    const float* bk     = (const float*)d_in[16];
    const float* Wq     = (const float*)d_in[17];
    const float* bq     = (const float*)d_in[18];
    const float* Wv     = (const float*)d_in[19];
    const float* bv     = (const float*)d_in[20];
    const float* a_rel  = (const float*)d_in[21];
    const float* m_rel  = (const float*)d_in[22];
    const float* p_rel  = (const float*)d_in[23];
    const float* skip   = (const float*)d_in[24];
    const float* Wa     = (const float*)d_in[25];
    const float* ba     = (const float*)d_in[26];
    const float* Wlin   = (const float*)d_in[27];
    const float* blin   = (const float*)d_in[28];

    char* ws = (char*)d_ws;
    float* out = (float*)d_out;

    precompA<<<(83464 + NM + 255) / 256, 256, 0, stream>>>(
        Wk, bk, Wv, bv, Wa, ba, Wlin, blin,
        a_rel, m_rel, p_rel, skip, bpre, Wq, ws);

    prep_scat<<<2344 + 403, 256, 0, stream>>>(
        src_dm, dst_dm, src_am, dst_am,
        Wpre_m, Wpre_d, Wpre_a, bpre, bq, Wlin, skip, ws);

    gemm_all<<<MB + DB + AB, 256, 0, stream>>>(
        x_movie, x_director, x_actor,
        (const unsigned short*)(ws + OFF_BT_Q),
        (const unsigned short*)(ws + OFF_BT_KAMV_D),
        (const unsigned short*)(ws + OFF_BT_KAMV_A),
        (const float*)(ws + OFF_BQ),
        (const float*)(ws + OFF_B_KAMV_D), (const float*)(ws + OFF_B_KAMV_A),
        (unsigned short*)(ws + OFF_Q0), (float*)(ws + OFF_SKIPB),
        (unsigned short*)(ws + OFF_KAMV_D), (unsigned short*)(ws + OFF_KAMV_A));

    agg_kernel<<<NM / 16, 256, 0, stream>>>(
        (const unsigned short*)(ws + OFF_Q0),
        (const char*)(ws + OFF_KAMV_D),
        (const int*)(ws + OFF_COUNTS), (const int*)(ws + OFF_SLOTS),
        (const float*)(ws + OFF_SKIPB),
        (const float*)(ws + OFF_WALS), (const float*)(ws + OFF_BFIN), out);
}

// Round 11
// 363.727 us; speedup vs baseline: 1.0889x; 1.0417x over previous
//
#include <hip/hip_runtime.h>
#include <hip/hip_bf16.h>
#include <math.h>

// ---------------------------------------------------------------------------
// Problem constants
// ---------------------------------------------------------------------------
#define NM 100000
#define ND 20000
#define NA 50000
#define EDG 300000
#define CAP 32    // max in-degree slots per movie node (Poisson(6): P(>32)~1.6e-14)

// gemm_all v2 (measured 88us) + fused edge scatter.
#define NTM 6250   // NM/16
#define NTD 1250   // ND/16
#define NTA 3125   // NA/16
#define MB  391    // ceil(6250/16) movie blocks (4 waves x 4 tiles)
#define DB  79     // ceil(1250/16)
#define AB  196    // ceil(3125/16)
#define GEMM_BLKS (MB + DB + AB)   // 666

typedef __attribute__((ext_vector_type(8))) short shortx8;
typedef __attribute__((ext_vector_type(4))) float floatx4;
typedef __attribute__((ext_vector_type(4))) int intx4;

__device__ __forceinline__ float bf2f(unsigned int u) {
    return __uint_as_float(u << 16);
}
__device__ __forceinline__ unsigned short f2bf(float f) {   // RNE (precomp only)
    unsigned int x = __float_as_uint(f);
    unsigned int r = x + 0x7fffu + ((x >> 16) & 1u);
    return (unsigned short)(r >> 16);
}
__device__ __forceinline__ unsigned short f2bf_fast(float f) {  // round-half-up
    return (unsigned short)((__float_as_uint(f) + 0x8000u) >> 16);
}
// pack 2 f32 -> dword [bf16(a) | bf16(b)<<16] : 2 add + 1 v_perm
__device__ __forceinline__ unsigned int pkbf2(float a, float b) {
    return __builtin_amdgcn_perm(__float_as_uint(b) + 0x8000u,
                                 __float_as_uint(a) + 0x8000u,
                                 0x07060302u);
}
// pack 8 f32 (two floatx4) -> shortx8 bf16, memory element order preserved
__device__ __forceinline__ shortx8 pack8(floatx4 a, floatx4 b) {
    intx4 r;
    r[0] = (int)pkbf2(a[0], a[1]);
    r[1] = (int)pkbf2(a[2], a[3]);
    r[2] = (int)pkbf2(b[0], b[1]);
    r[3] = (int)pkbf2(b[2], b[3]);
    return __builtin_bit_cast(shortx8, r);
}
__device__ __forceinline__ float gelu_exact(float x) {
    return 0.5f * x * (1.0f + erff(x * 0.70710678118654752f));
}

// ---------------------------------------------------------------------------
// Workspace layout (bytes)
// ---------------------------------------------------------------------------
static const size_t OFF_BT_Q      = 0;          // [2][144][128] bf16, HALF-MAJOR
static const size_t OFF_BT_KAMV_D = 73728;      // 256x128 bf16 (rows 0-127 ka, 128-255 mv)
static const size_t OFF_BT_KAMV_A = 139264;     // 256x128 bf16
static const size_t OFF_WKA_D     = 204800;     // 128x128 f32 TRANSPOSED [nc][e]
static const size_t OFF_WVM_D     = 270336;     // 128x128 f32 T
static const size_t OFF_WKA_A     = 335872;     // 128x128 f32 T
static const size_t OFF_WVM_A     = 401408;     // 128x128 f32 T
static const size_t OFF_BQ        = 466944;     // 144 f32
static const size_t OFF_B_KAMV_D  = 467520;     // 256 f32
static const size_t OFF_B_KAMV_A  = 468544;     // 256 f32
static const size_t OFF_BKA_D     = 469568;     // 128 f32
static const size_t OFF_BVM_D     = 470080;     // 128 f32
static const size_t OFF_BKA_A     = 470592;     // 128 f32
static const size_t OFF_BVM_A     = 471104;     // 128 f32
static const size_t OFF_WALS      = 471616;     // 128x8 f32 (g·Wa[0]@Wlin)
static const size_t OFF_BFIN      = 475712;     // 8 f32
static const size_t OFF_Q0        = 524288;     // NM*128 bf16   (25.6 MB)
static const size_t OFF_SKIPB     = 26124288;   // NM*8 f32      (3.2 MB)
static const size_t OFF_WQT       = 26124288;   // 128x128 f32 — overlaps SKIPB
static const size_t OFF_KAMV_D    = 29324288;   // ND*256 bf16   (10.24 MB)
static const size_t OFF_KAMV_A    = 39564288;   // NA*256 bf16   (25.6 MB)
static const size_t OFF_COUNTS    = 65164288;   // NM int32
static const size_t OFF_SLOTS     = 65564288;   // NM*CAP int32  (12.8 MB)
#define KAMV_A_DELTA 10240000   // OFF_KAMV_A - OFF_KAMV_D

// ---------------------------------------------------------------------------
// K0a: fold a_rel/m_rel/p·scale into Wk/Wv (stored TRANSPOSED); transpose Wq;
// epilogue tables; zero counts
// ---------------------------------------------------------------------------
__global__ __launch_bounds__(256) void precompA(
    const float* __restrict__ Wk, const float* __restrict__ bk,
    const float* __restrict__ Wv, const float* __restrict__ bv,
    const float* __restrict__ Wa, const float* __restrict__ ba,
    const float* __restrict__ Wlin, const float* __restrict__ blin,
    const float* __restrict__ a_rel, const float* __restrict__ m_rel,
    const float* __restrict__ p_rel, const float* __restrict__ skip,
    const float* __restrict__ bpre, const float* __restrict__ Wq,
    char* __restrict__ ws)
{
    int tid = blockIdx.x * 256 + threadIdx.x;
    if (tid < 65536) {
        int mat = tid >> 14, rem = tid & 16383;
        int e = rem >> 7, hf = rem & 127, h = hf >> 4, f = hf & 15;
        const float* Wsrc; const float* R; float sc; float* dst;
        if (mat == 0)      { Wsrc = Wk + 16384; R = a_rel;        sc = p_rel[h]     * 0.25f; dst = (float*)(ws + OFF_WKA_D); }
        else if (mat == 1) { Wsrc = Wv + 16384; R = m_rel;        sc = 1.0f;                 dst = (float*)(ws + OFF_WVM_D); }
        else if (mat == 2) { Wsrc = Wk + 32768; R = a_rel + 2048; sc = p_rel[8 + h] * 0.25f; dst = (float*)(ws + OFF_WKA_A); }
        else               { Wsrc = Wv + 32768; R = m_rel + 2048; sc = 1.0f;                 dst = (float*)(ws + OFF_WVM_A); }
        float s = 0.0f;
        for (int d = 0; d < 16; d++)
            s += Wsrc[e * 128 + h * 16 + d] * R[h * 256 + d * 16 + f];
        dst[hf * 128 + e] = s * sc;          // TRANSPOSED store
    } else if (tid < 66048) {
        int idx = tid - 65536;
        int mat = idx >> 7, hf = idx & 127, h = hf >> 4, f = hf & 15;
        const float* bsrc; const float* R; float sc; float* dst;
        if (mat == 0)      { bsrc = bk + 128; R = a_rel;        sc = p_rel[h]     * 0.25f; dst = (float*)(ws + OFF_BKA_D); }
        else if (mat == 1) { bsrc = bv + 128; R = m_rel;        sc = 1.0f;                 dst = (float*)(ws + OFF_BVM_D); }
        else if (mat == 2) { bsrc = bk + 256; R = a_rel + 2048; sc = p_rel[8 + h] * 0.25f; dst = (float*)(ws + OFF_BKA_A); }
        else               { bsrc = bv + 256; R = m_rel + 2048; sc = 1.0f;                 dst = (float*)(ws + OFF_BVM_A); }
        float s = 0.0f;
        for (int d = 0; d < 16; d++)
            s += bsrc[h * 16 + d] * R[h * 256 + d * 16 + f];
        dst[hf] = s * sc;
    } else if (tid < 67072) {
        // WaLs[j][c] = g * sum_o Wa[0][j][o] * Wlin[o][c]
        int idx = tid - 66048;
        int j = idx >> 3, c = idx & 7;
        float g = 1.0f / (1.0f + __expf(-skip[0]));
        float s = 0.0f;
        for (int o = 0; o < 128; o++)
            s += Wa[j * 128 + o] * Wlin[o * 8 + c];
        ((float*)(ws + OFF_WALS))[j * 8 + c] = g * s;
    } else if (tid < 67080) {
        int c = tid - 67072;
        float g = 1.0f / (1.0f + __expf(-skip[0]));
        float s1 = 0.0f, s2 = 0.0f;
        for (int o = 0; o < 128; o++) {
            s1 += ba[o]   * Wlin[o * 8 + c];
            s2 += bpre[o] * Wlin[o * 8 + c];
        }
        ((float*)(ws + OFF_BFIN))[c] = g * s1 + (1.0f - g) * s2 + blin[c];
    } else if (tid < 83464) {
        // WqT[n][e] = Wq[0][e][n]
        int i = tid - 67080;
        int n = i >> 7, e = i & 127;
        ((float*)(ws + OFF_WQT))[n * 128 + e] = Wq[e * 128 + n];
    } else if (tid < 83464 + NM) {
        ((int*)(ws + OFF_COUNTS))[tid - 83464] = 0;   // zero edge counters
    }
}

// ---------------------------------------------------------------------------
// contiguous-dot helper: 128-elem dot of two 16B-aligned f32 streams
// ---------------------------------------------------------------------------
__device__ __forceinline__ float dot128(const float* __restrict__ a,
                                        const float* __restrict__ b) {
    const floatx4* x = (const floatx4*)a;
    const floatx4* y = (const floatx4*)b;
    float s = 0.0f;
    #pragma unroll
    for (int i = 0; i < 32; i++) {
        floatx4 u = x[i], v = y[i];
        s += u[0] * v[0] + u[1] * v[1] + u[2] * v[2] + u[3] * v[3];
    }
    return s;
}

// ---------------------------------------------------------------------------
// K0b: precompB only (scatter moved into gemm_all). 403 blocks.
// ---------------------------------------------------------------------------
__global__ __launch_bounds__(256) void prep_scat(
    const float* __restrict__ Wpre_m, const float* __restrict__ Wpre_d,
    const float* __restrict__ Wpre_a, const float* __restrict__ bpre,
    const float* __restrict__ bq, const float* __restrict__ Wlin,
    const float* __restrict__ skip,
    char* __restrict__ ws)
{
    int tid = blockIdx.x * 256 + threadIdx.x;
    const float* WKA_D = (const float*)(ws + OFF_WKA_D);
    const float* WVM_D = (const float*)(ws + OFF_WVM_D);
    const float* WKA_A = (const float*)(ws + OFF_WKA_A);
    const float* WVM_A = (const float*)(ws + OFF_WVM_A);
    const float* WqT   = (const float*)(ws + OFF_WQT);

    if (tid < 36864) {
        int n = tid >> 8, c = tid & 255;
        float s = 0.0f;
        if (n < 128) {
            s = dot128(Wpre_m + c * 128, WqT + n * 128);
        } else if (n < 136) {
            int cc = n - 128;
            float g = 1.0f / (1.0f + __expf(-skip[0]));
            for (int e = 0; e < 128; e++)
                s += Wpre_m[c * 128 + e] * Wlin[e * 8 + cc];
            s *= (1.0f - g);
        }
        // HALF-MAJOR store: [c>>7][n][c&127]
        ((unsigned short*)(ws + OFF_BT_Q))[(c >> 7) * 18432 + n * 128 + (c & 127)] = f2bf(s);
    } else if (tid < 69632) {
        int idx = tid - 36864;
        int nrow = idx >> 7, c = idx & 127;
        const float* WfT = (nrow < 128) ? WKA_D : WVM_D;
        int nc = nrow & 127;
        float s = dot128(Wpre_d + c * 128, WfT + nc * 128);
        ((unsigned short*)(ws + OFF_BT_KAMV_D))[nrow * 128 + c] = f2bf(s);
    } else if (tid < 102400) {
        int idx = tid - 69632;
        int nrow = idx >> 7, c = idx & 127;
        const float* WfT = (nrow < 128) ? WKA_A : WVM_A;
        int nc = nrow & 127;
        float s = dot128(Wpre_a + c * 128, WfT + nc * 128);
        ((unsigned short*)(ws + OFF_BT_KAMV_A))[nrow * 128 + c] = f2bf(s);
    } else if (tid < 102544) {
        int n = tid - 102400;
        float s = 0.0f;
        if (n < 128) s = dot128(bpre, WqT + n * 128) + bq[n];
        ((float*)(ws + OFF_BQ))[n] = s;
    } else if (tid < 102800) {
        int nrow = tid - 102544;
        const float* WfT = (nrow < 128) ? WKA_D : WVM_D;
        const float* bf_ = (nrow < 128) ? (const float*)(ws + OFF_BKA_D) : (const float*)(ws + OFF_BVM_D);
        int nc = nrow & 127;
        ((float*)(ws + OFF_B_KAMV_D))[nrow] = dot128(bpre + 128, WfT + nc * 128) + bf_[nc];
    } else if (tid < 103056) {
        int nrow = tid - 102800;
        const float* WfT = (nrow < 128) ? WKA_A : WVM_A;
        const float* bf_ = (nrow < 128) ? (const float*)(ws + OFF_BKA_A) : (const float*)(ws + OFF_BVM_A);
        int nc = nrow & 127;
        ((float*)(ws + OFF_B_KAMV_A))[nrow] = dot128(bpre + 256, WfT + nc * 128) + bf_[nc];
    }
}

// ---------------------------------------------------------------------------
// gemm_all v2 + fused edge scatter.
// The 600K-edge scatter (independent of GEMM inputs; consumed only by agg)
// runs as a grid-stride prologue across the 666 gemm blocks — its atomics
// execute in gemm's idle latency slack (VALUBusy was 5%).
// ---------------------------------------------------------------------------
#define MFMA16(a, b, c) __builtin_amdgcn_mfma_f32_16x16x32_bf16(a, b, c, 0, 0, 0)

__global__ __launch_bounds__(256, 2) void gemm_all(
    const float* __restrict__ xm, const float* __restrict__ xd,
    const float* __restrict__ xa,
    const unsigned short* __restrict__ btq,   // [2][144][128] half-major
    const unsigned short* __restrict__ btd,   // [256][128]
    const unsigned short* __restrict__ bta,   // [256][128]
    const float* __restrict__ bq,
    const float* __restrict__ bbd, const float* __restrict__ bba,
    const int* __restrict__ src_dm, const int* __restrict__ dst_dm,
    const int* __restrict__ src_am, const int* __restrict__ dst_am,
    int* __restrict__ counts, int* __restrict__ slots,
    unsigned short* __restrict__ q0, float* __restrict__ skipb,
    unsigned short* __restrict__ outd, unsigned short* __restrict__ outa)
{
    __shared__ unsigned short b_lds[288 * 136];   // 78336 B (d/a use first 256 rows)
    int tid = threadIdx.x;
    int w = tid >> 6, lane = tid & 63;
    int quad = lane >> 4, low = lane & 15;
    int bx = blockIdx.x;

    // ---- fused edge scatter (grid-stride over all 666 blocks) ----
    for (int t = bx * 256 + tid; t < 2 * EDG; t += GEMM_BLKS * 256) {
        int src, dst, delta;
        if (t < EDG) { src = src_dm[t];       dst = dst_dm[t];       delta = 0; }
        else         { src = src_am[t - EDG]; dst = dst_am[t - EDG]; delta = KAMV_A_DELTA; }
        int pos = atomicAdd(&counts[dst], 1);
        if (pos < CAP) slots[(size_t)dst * CAP + pos] = src * 512 + delta;
    }

    if (bx < MB) {
        // ---------------- movie: q0 + skipb ----------------
        #pragma unroll
        for (int it = 0; it < 18; it++) {
            int idx = it * 256 + tid, r = idx >> 4, ch = idx & 15;
            *(intx4*)&b_lds[r * 136 + ch * 8] =
                *(const intx4*)&btq[(size_t)r * 128 + ch * 8];
        }
        __syncthreads();
        float bqr[9];
        #pragma unroll
        for (int j = 0; j < 9; j++) bqr[j] = bq[j * 16 + low];

        int t0 = (bx * 4 + w) * 4;
        floatx4 st[16];
        {   // stage first tile
            int te = t0 < NTM ? t0 : NTM - 1;
            const float* Ap = xm + (size_t)(te * 16 + low) * 256 + quad * 8;
            #pragma unroll
            for (int ks = 0; ks < 8; ks++) {
                st[2 * ks]     = *(const floatx4*)(Ap + ks * 32);
                st[2 * ks + 1] = *(const floatx4*)(Ap + ks * 32 + 4);
            }
        }
        #pragma unroll
        for (int i = 0; i < 4; i++) {
            int t = t0 + i;
            shortx8 fa[8];
            #pragma unroll
            for (int ks = 0; ks < 8; ks++) fa[ks] = pack8(st[2 * ks], st[2 * ks + 1]);
            {   // prefetch next tile (clamped; in flight during MFMAs)
                int tn = t + 1 < NTM ? t + 1 : NTM - 1;
                const float* Ap = xm + (size_t)(tn * 16 + low) * 256 + quad * 8;
                #pragma unroll
                for (int ks = 0; ks < 8; ks++) {
                    st[2 * ks]     = *(const floatx4*)(Ap + ks * 32);
                    st[2 * ks + 1] = *(const floatx4*)(Ap + ks * 32 + 4);
                }
            }
            floatx4 acc[9] = {};
            #pragma unroll
            for (int ks = 0; ks < 8; ks++) {
                int rb = (ks >> 2) * 19584 + low * 136 + (ks & 3) * 32 + quad * 8;
                #pragma unroll
                for (int j = 0; j < 9; j++) {
                    shortx8 b = *(const shortx8*)&b_lds[rb + j * 2176];
                    acc[j] = MFMA16(fa[ks], b, acc[j]);
                }
            }
            if (t < NTM) {
                int row0 = t * 16 + quad * 4;
                #pragma unroll
                for (int j = 0; j < 8; j++) {
                    int col = j * 16 + low;
                    #pragma unroll
                    for (int r = 0; r < 4; r++)
                        q0[(size_t)(row0 + r) * 128 + col] = f2bf_fast(acc[j][r] + bqr[j]);
                }
                if (low < 8) {
                    #pragma unroll
                    for (int r = 0; r < 4; r++)
                        skipb[(size_t)(row0 + r) * 8 + low] = acc[8][r] + bqr[8];
                }
            }
        }
    } else {
        // ---------------- director / actor: ka|mv ----------------
        const float* A; const unsigned short* BT; const float* bias;
        unsigned short* outb; int ntt, wid;
        if (bx < MB + DB) { A = xd; BT = btd; bias = bbd; outb = outd; ntt = NTD; wid = (bx - MB) * 4 + w; }
        else              { A = xa; BT = bta; bias = bba; outb = outa; ntt = NTA; wid = (bx - MB - DB) * 4 + w; }
        #pragma unroll
        for (int it = 0; it < 16; it++) {
            int idx = it * 256 + tid, r = idx >> 4, ch = idx & 15;
            *(intx4*)&b_lds[r * 136 + ch * 8] =
                *(const intx4*)&BT[(size_t)r * 128 + ch * 8];
        }
        __syncthreads();
        float biasr[16];
        #pragma unroll
        for (int j = 0; j < 16; j++) biasr[j] = bias[j * 16 + low];

        int t0 = wid * 4;
        floatx4 st[8];
        {
            int te = t0 < ntt ? t0 : ntt - 1;
            const float* Ap = A + (size_t)(te * 16 + low) * 128 + quad * 8;
            #pragma unroll
            for (int ks = 0; ks < 4; ks++) {
                st[2 * ks]     = *(const floatx4*)(Ap + ks * 32);
                st[2 * ks + 1] = *(const floatx4*)(Ap + ks * 32 + 4);
            }
        }
        #pragma unroll
        for (int i = 0; i < 4; i++) {
            int t = t0 + i;
            shortx8 fa[4];
            #pragma unroll
            for (int ks = 0; ks < 4; ks++) fa[ks] = pack8(st[2 * ks], st[2 * ks + 1]);
            {
                int tn = t + 1 < ntt ? t + 1 : ntt - 1;
                const float* Ap = A + (size_t)(tn * 16 + low) * 128 + quad * 8;
                #pragma unroll
                for (int ks = 0; ks < 4; ks++) {
                    st[2 * ks]     = *(const floatx4*)(Ap + ks * 32);
                    st[2 * ks + 1] = *(const floatx4*)(Ap + ks * 32 + 4);
                }
            }
            floatx4 acc[16] = {};
            #pragma unroll
            for (int ks = 0; ks < 4; ks++) {
                int rb = low * 136 + ks * 32 + quad * 8;
                #pragma unroll
                for (int j = 0; j < 16; j++) {
                    shortx8 b = *(const shortx8*)&b_lds[rb + j * 2176];
                    acc[j] = MFMA16(fa[ks], b, acc[j]);
                }
            }
            if (t < ntt) {
                int row0 = t * 16 + quad * 4;
                #pragma unroll
                for (int j = 0; j < 16; j++) {
                    int col = j * 16 + low;
                    #pragma unroll
                    for (int r = 0; r < 4; r++)
                        outb[(size_t)(row0 + r) * 256 + col] = f2bf_fast(acc[j][r] + biasr[j]);
                }
            }
        }
    }
}

// ---------------------------------------------------------------------------
// Aggregation: 16 lanes/node, 4 nodes/wave, 2-deep edge prefetch.
// ---------------------------------------------------------------------------
__global__ __launch_bounds__(256) void agg_kernel(
    const unsigned short* __restrict__ q0,
    const char* __restrict__ kamv0,      // = ws + OFF_KAMV_D
    const int* __restrict__ counts, const int* __restrict__ slots,
    const float* __restrict__ skipb,
    const float* __restrict__ WaLs, const float* __restrict__ bfin,
    float* __restrict__ out)
{
    __shared__ float wals[1032];   // [c][j*16+L] transposed-interleaved + bfin
    for (int i = threadIdx.x; i < 1024; i += 256) {
        int c = i >> 7, rem = i & 127, j = rem >> 4, L = rem & 15;
        wals[i] = WaLs[(L * 8 + j) * 8 + c];
    }
    if (threadIdx.x < 8) wals[1024 + threadIdx.x] = bfin[threadIdx.x];
    __syncthreads();

    int lane = threadIdx.x & 63;
    int grp = lane >> 4;
    int L   = lane & 15;
    int n = blockIdx.x * 16 + (threadIdx.x >> 6) * 4 + grp;

    intx4 qv = *(const intx4*)(q0 + (size_t)n * 128 + L * 8);
    float qf[8];
    #pragma unroll
    for (int d = 0; d < 4; d++) {
        unsigned int u = (unsigned int)qv[d];
        qf[2 * d]     = __uint_as_float(u << 16);
        qf[2 * d + 1] = __uint_as_float(u & 0xffff0000u);
    }

    int cnt = counts[n];
    cnt = cnt < 0 ? 0 : (cnt > CAP ? CAP : cnt);
    int s0 = slots[(size_t)n * CAP + L];

    float acc[8] = {0, 0, 0, 0, 0, 0, 0, 0};
    float den = 0.0f;
    if (cnt > 0) {
        // edge 0
        int off0 = __shfl(s0, lane & 48);
        const char* p0 = kamv0 + off0;
        intx4 ku = *(const intx4*)(p0 + L * 16);
        intx4 mu = *(const intx4*)(p0 + 256 + L * 16);
        // edge 1 (clamped)
        int e1 = 1 < cnt ? 1 : cnt - 1;
        int off1 = __shfl(s0, (lane & 48) + (e1 & 15));
        if (__builtin_expect(e1 >= 16, 0)) off1 = slots[(size_t)n * CAP + e1];
        const char* p1 = kamv0 + off1;
        intx4 kun = *(const intx4*)(p1 + L * 16);
        intx4 mun = *(const intx4*)(p1 + 256 + L * 16);

        for (int i = 0; i < cnt; i++) {
            // issue edge i+2 (clamped) -> consumed two iterations later
            int e2 = (i + 2 < cnt) ? i + 2 : cnt - 1;
            int off2 = __shfl(s0, (lane & 48) + (e2 & 15));
            if (__builtin_expect(e2 >= 16, 0)) off2 = slots[(size_t)n * CAP + e2];
            const char* p2 = kamv0 + off2;
            intx4 ku2 = *(const intx4*)(p2 + L * 16);
            intx4 mu2 = *(const intx4*)(p2 + 256 + L * 16);

            float ph = 0.0f;
            #pragma unroll
            for (int d = 0; d < 4; d++) {
                unsigned int u = (unsigned int)ku[d];
                ph += qf[2 * d]     * __uint_as_float(u << 16);
                ph += qf[2 * d + 1] * __uint_as_float(u & 0xffff0000u);
            }
            float pf = ph + __shfl_xor(ph, 1);
            float wgt = __expf(fminf(pf, 60.0f));
            den += wgt;
            #pragma unroll
            for (int d = 0; d < 4; d++) {
                unsigned int u = (unsigned int)mu[d];
                acc[2 * d]     += wgt * __uint_as_float(u << 16);
                acc[2 * d + 1] += wgt * __uint_as_float(u & 0xffff0000u);
            }
            ku = kun; mu = mun; kun = ku2; mun = mu2;
        }
    }
    float inv = 1.0f / fmaxf(den, 1e-16f);

    float part[8] = {0, 0, 0, 0, 0, 0, 0, 0};
    #pragma unroll
    for (int j = 0; j < 8; j++) {
        float u = gelu_exact(acc[j] * inv);
        #pragma unroll
        for (int c = 0; c < 8; c++)
            part[c] += u * wals[c * 128 + j * 16 + L];
    }

    bool b0 = lane & 1, b1 = lane & 2, b2 = lane & 4;
    float t1[4], t2[2], t3;
    #pragma unroll
    for (int k = 0; k < 4; k++) {
        float send = b0 ? part[k] : part[4 + k];
        float got  = __shfl_xor(send, 1);
        t1[k] = (b0 ? part[4 + k] : part[k]) + got;
    }
    #pragma unroll
    for (int k = 0; k < 2; k++) {
        float send = b1 ? t1[k] : t1[2 + k];
        float got  = __shfl_xor(send, 2);
        t2[k] = (b1 ? t1[2 + k] : t1[k]) + got;
    }
    {
        float send = b2 ? t2[0] : t2[1];
        float got  = __shfl_xor(send, 4);
        t3 = (b2 ? t2[1] : t2[0]) + got;
    }
    t3 += __shfl_xor(t3, 8);
    if (L < 8) {
        int c = 4 * (L & 1) + 2 * ((L >> 1) & 1) + ((L >> 2) & 1);
        out[(size_t)n * 8 + c] = t3 + skipb[(size_t)n * 8 + c] + wals[1024 + c];
    }
}

// ---------------------------------------------------------------------------
// Host launch — 4 dispatches (scatter now lives inside gemm_all)
// ---------------------------------------------------------------------------
extern "C" void kernel_launch(void* const* d_in, const int* in_sizes, int n_in,
                              void* d_out, int out_size, void* d_ws, size_t ws_size,
                              hipStream_t stream) {
    (void)in_sizes; (void)n_in; (void)out_size; (void)ws_size;
    const float* x_movie    = (const float*)d_in[0];
    const float* x_director = (const float*)d_in[1];
    const float* x_actor    = (const float*)d_in[2];
    const int* src_dm = (const int*)d_in[3];
    const int* dst_dm = (const int*)d_in[4];
    const int* src_am = (const int*)d_in[5];
    const int* dst_am = (const int*)d_in[6];
    const float* Wpre_m = (const float*)d_in[11];
    const float* Wpre_d = (const float*)d_in[12];
    const float* Wpre_a = (const float*)d_in[13];
    const float* bpre   = (const float*)d_in[14];
    const float* Wk     = (const float*)d_in[15];
    const float* bk     = (const float*)d_in[16];
    const float* Wq     = (const float*)d_in[17];
    const float* bq     = (const float*)d_in[18];
    const float* Wv     = (const float*)d_in[19];
    const float* bv     = (const float*)d_in[20];
    const float* a_rel  = (const float*)d_in[21];
    const float* m_rel  = (const float*)d_in[22];
    const float* p_rel  = (const float*)d_in[23];
    const float* skip   = (const float*)d_in[24];
    const float* Wa     = (const float*)d_in[25];
    const float* ba     = (const float*)d_in[26];
    const float* Wlin   = (const float*)d_in[27];
    const float* blin   = (const float*)d_in[28];

    char* ws = (char*)d_ws;
    float* out = (float*)d_out;

    precompA<<<(83464 + NM + 255) / 256, 256, 0, stream>>>(
        Wk, bk, Wv, bv, Wa, ba, Wlin, blin,
        a_rel, m_rel, p_rel, skip, bpre, Wq, ws);

    prep_scat<<<403, 256, 0, stream>>>(
        Wpre_m, Wpre_d, Wpre_a, bpre, bq, Wlin, skip, ws);

    gemm_all<<<GEMM_BLKS, 256, 0, stream>>>(
        x_movie, x_director, x_actor,
        (const unsigned short*)(ws + OFF_BT_Q),
        (const unsigned short*)(ws + OFF_BT_KAMV_D),
        (const unsigned short*)(ws + OFF_BT_KAMV_A),
        (const float*)(ws + OFF_BQ),
        (const float*)(ws + OFF_B_KAMV_D), (const float*)(ws + OFF_B_KAMV_A),
        src_dm, dst_dm, src_am, dst_am,
        (int*)(ws + OFF_COUNTS), (int*)(ws + OFF_SLOTS),
        (unsigned short*)(ws + OFF_Q0), (float*)(ws + OFF_SKIPB),
        (unsigned short*)(ws + OFF_KAMV_D), (unsigned short*)(ws + OFF_KAMV_A));

    agg_kernel<<<NM / 16, 256, 0, stream>>>(
        (const unsigned short*)(ws + OFF_Q0),
        (const char*)(ws + OFF_KAMV_D),
        (const int*)(ws + OFF_COUNTS), (const int*)(ws + OFF_SLOTS),
        (const float*)(ws + OFF_SKIPB),
        (const float*)(ws + OFF_WALS), (const float*)(ws + OFF_BFIN), out);
}

// Round 13
// 359.397 us; speedup vs baseline: 1.1020x; 1.0120x over previous
//
#include <hip/hip_runtime.h>
#include <hip/hip_bf16.h>
#include <math.h>

// ---------------------------------------------------------------------------
// Problem constants
// ---------------------------------------------------------------------------
#define NM 100000
#define ND 20000
#define NA 50000
#define EDG 300000
#define CAP 32    // max in-degree slots per movie node (Poisson(6): P(>32)~1.6e-14)

// gemm_all v2 + scatter interleaved into the tile loop (1 edge/thread/iter).
#define NTM 6250   // NM/16
#define NTD 1250   // ND/16
#define NTA 3125   // NA/16
#define MB  391    // ceil(6250/16) movie blocks (4 waves x 4 tiles)
#define DB  79     // ceil(1250/16)
#define AB  196    // ceil(3125/16)
#define GEMM_BLKS (MB + DB + AB)   // 666

typedef __attribute__((ext_vector_type(8))) short shortx8;
typedef __attribute__((ext_vector_type(4))) float floatx4;
typedef __attribute__((ext_vector_type(4))) int intx4;

__device__ __forceinline__ float bf2f(unsigned int u) {
    return __uint_as_float(u << 16);
}
__device__ __forceinline__ unsigned short f2bf(float f) {   // RNE (precomp only)
    unsigned int x = __float_as_uint(f);
    unsigned int r = x + 0x7fffu + ((x >> 16) & 1u);
    return (unsigned short)(r >> 16);
}
__device__ __forceinline__ unsigned short f2bf_fast(float f) {  // round-half-up
    return (unsigned short)((__float_as_uint(f) + 0x8000u) >> 16);
}
// pack 2 f32 -> dword [bf16(a) | bf16(b)<<16] : 2 add + 1 v_perm
__device__ __forceinline__ unsigned int pkbf2(float a, float b) {
    return __builtin_amdgcn_perm(__float_as_uint(b) + 0x8000u,
                                 __float_as_uint(a) + 0x8000u,
                                 0x07060302u);
}
// pack 8 f32 (two floatx4) -> shortx8 bf16, memory element order preserved
__device__ __forceinline__ shortx8 pack8(floatx4 a, floatx4 b) {
    intx4 r;
    r[0] = (int)pkbf2(a[0], a[1]);
    r[1] = (int)pkbf2(a[2], a[3]);
    r[2] = (int)pkbf2(b[0], b[1]);
    r[3] = (int)pkbf2(b[2], b[3]);
    return __builtin_bit_cast(shortx8, r);
}
__device__ __forceinline__ float gelu_exact(float x) {
    return 0.5f * x * (1.0f + erff(x * 0.70710678118654752f));
}

// ---------------------------------------------------------------------------
// Workspace layout (bytes)
// ---------------------------------------------------------------------------
static const size_t OFF_BT_Q      = 0;          // [2][144][128] bf16, HALF-MAJOR
static const size_t OFF_BT_KAMV_D = 73728;      // 256x128 bf16 (rows 0-127 ka, 128-255 mv)
static const size_t OFF_BT_KAMV_A = 139264;     // 256x128 bf16
static const size_t OFF_WKA_D     = 204800;     // 128x128 f32 TRANSPOSED [nc][e]
static const size_t OFF_WVM_D     = 270336;     // 128x128 f32 T
static const size_t OFF_WKA_A     = 335872;     // 128x128 f32 T
static const size_t OFF_WVM_A     = 401408;     // 128x128 f32 T
static const size_t OFF_BQ        = 466944;     // 144 f32
static const size_t OFF_B_KAMV_D  = 467520;     // 256 f32
static const size_t OFF_B_KAMV_A  = 468544;     // 256 f32
static const size_t OFF_BKA_D     = 469568;     // 128 f32
static const size_t OFF_BVM_D     = 470080;     // 128 f32
static const size_t OFF_BKA_A     = 470592;     // 128 f32
static const size_t OFF_BVM_A     = 471104;     // 128 f32
static const size_t OFF_WALS      = 471616;     // 128x8 f32 (g·Wa[0]@Wlin)
static const size_t OFF_BFIN      = 475712;     // 8 f32
static const size_t OFF_Q0        = 524288;     // NM*128 bf16   (25.6 MB)
static const size_t OFF_SKIPB     = 26124288;   // NM*8 f32      (3.2 MB)
static const size_t OFF_WQT       = 26124288;   // 128x128 f32 — overlaps SKIPB
static const size_t OFF_KAMV_D    = 29324288;   // ND*256 bf16   (10.24 MB)
static const size_t OFF_KAMV_A    = 39564288;   // NA*256 bf16   (25.6 MB)
static const size_t OFF_COUNTS    = 65164288;   // NM int32
static const size_t OFF_SLOTS     = 65564288;   // NM*CAP int32  (12.8 MB)
#define KAMV_A_DELTA 10240000   // OFF_KAMV_A - OFF_KAMV_D

// scatter one edge chunk: global edge index t (covers both relations)
__device__ __forceinline__ void scat_one(int t,
    const int* __restrict__ src_dm, const int* __restrict__ dst_dm,
    const int* __restrict__ src_am, const int* __restrict__ dst_am,
    int* __restrict__ counts, int* __restrict__ slots) {
    if (t < 2 * EDG) {
        int src, dst, delta;
        if (t < EDG) { src = src_dm[t];       dst = dst_dm[t];       delta = 0; }
        else         { src = src_am[t - EDG]; dst = dst_am[t - EDG]; delta = KAMV_A_DELTA; }
        int pos = atomicAdd(&counts[dst], 1);
        if (pos < CAP) slots[(size_t)dst * CAP + pos] = src * 512 + delta;
    }
}

// ---------------------------------------------------------------------------
// K0a: fold a_rel/m_rel/p·scale into Wk/Wv (stored TRANSPOSED); transpose Wq;
// epilogue tables; zero counts
// ---------------------------------------------------------------------------
__global__ __launch_bounds__(256) void precompA(
    const float* __restrict__ Wk, const float* __restrict__ bk,
    const float* __restrict__ Wv, const float* __restrict__ bv,
    const float* __restrict__ Wa, const float* __restrict__ ba,
    const float* __restrict__ Wlin, const float* __restrict__ blin,
    const float* __restrict__ a_rel, const float* __restrict__ m_rel,
    const float* __restrict__ p_rel, const float* __restrict__ skip,
    const float* __restrict__ bpre, const float* __restrict__ Wq,
    char* __restrict__ ws)
{
    int tid = blockIdx.x * 256 + threadIdx.x;
    if (tid < 65536) {
        int mat = tid >> 14, rem = tid & 16383;
        int e = rem >> 7, hf = rem & 127, h = hf >> 4, f = hf & 15;
        const float* Wsrc; const float* R; float sc; float* dst;
        if (mat == 0)      { Wsrc = Wk + 16384; R = a_rel;        sc = p_rel[h]     * 0.25f; dst = (float*)(ws + OFF_WKA_D); }
        else if (mat == 1) { Wsrc = Wv + 16384; R = m_rel;        sc = 1.0f;                 dst = (float*)(ws + OFF_WVM_D); }
        else if (mat == 2) { Wsrc = Wk + 32768; R = a_rel + 2048; sc = p_rel[8 + h] * 0.25f; dst = (float*)(ws + OFF_WKA_A); }
        else               { Wsrc = Wv + 32768; R = m_rel + 2048; sc = 1.0f;                 dst = (float*)(ws + OFF_WVM_A); }
        float s = 0.0f;
        for (int d = 0; d < 16; d++)
            s += Wsrc[e * 128 + h * 16 + d] * R[h * 256 + d * 16 + f];
        dst[hf * 128 + e] = s * sc;          // TRANSPOSED store
    } else if (tid < 66048) {
        int idx = tid - 65536;
        int mat = idx >> 7, hf = idx & 127, h = hf >> 4, f = hf & 15;
        const float* bsrc; const float* R; float sc; float* dst;
        if (mat == 0)      { bsrc = bk + 128; R = a_rel;        sc = p_rel[h]     * 0.25f; dst = (float*)(ws + OFF_BKA_D); }
        else if (mat == 1) { bsrc = bv + 128; R = m_rel;        sc = 1.0f;                 dst = (float*)(ws + OFF_BVM_D); }
        else if (mat == 2) { bsrc = bk + 256; R = a_rel + 2048; sc = p_rel[8 + h] * 0.25f; dst = (float*)(ws + OFF_BKA_A); }
        else               { bsrc = bv + 256; R = m_rel + 2048; sc = 1.0f;                 dst = (float*)(ws + OFF_BVM_A); }
        float s = 0.0f;
        for (int d = 0; d < 16; d++)
            s += bsrc[h * 16 + d] * R[h * 256 + d * 16 + f];
        dst[hf] = s * sc;
    } else if (tid < 67072) {
        // WaLs[j][c] = g * sum_o Wa[0][j][o] * Wlin[o][c]
        int idx = tid - 66048;
        int j = idx >> 3, c = idx & 7;
        float g = 1.0f / (1.0f + __expf(-skip[0]));
        float s = 0.0f;
        for (int o = 0; o < 128; o++)
            s += Wa[j * 128 + o] * Wlin[o * 8 + c];
        ((float*)(ws + OFF_WALS))[j * 8 + c] = g * s;
    } else if (tid < 67080) {
        int c = tid - 67072;
        float g = 1.0f / (1.0f + __expf(-skip[0]));
        float s1 = 0.0f, s2 = 0.0f;
        for (int o = 0; o < 128; o++) {
            s1 += ba[o]   * Wlin[o * 8 + c];
            s2 += bpre[o] * Wlin[o * 8 + c];
        }
        ((float*)(ws + OFF_BFIN))[c] = g * s1 + (1.0f - g) * s2 + blin[c];
    } else if (tid < 83464) {
        // WqT[n][e] = Wq[0][e][n]
        int i = tid - 67080;
        int n = i >> 7, e = i & 127;
        ((float*)(ws + OFF_WQT))[n * 128 + e] = Wq[e * 128 + n];
    } else if (tid < 83464 + NM) {
        ((int*)(ws + OFF_COUNTS))[tid - 83464] = 0;   // zero edge counters
    }
}

// ---------------------------------------------------------------------------
// contiguous-dot helper: 128-elem dot of two 16B-aligned f32 streams
// ---------------------------------------------------------------------------
__device__ __forceinline__ float dot128(const float* __restrict__ a,
                                        const float* __restrict__ b) {
    const floatx4* x = (const floatx4*)a;
    const floatx4* y = (const floatx4*)b;
    float s = 0.0f;
    #pragma unroll
    for (int i = 0; i < 32; i++) {
        floatx4 u = x[i], v = y[i];
        s += u[0] * v[0] + u[1] * v[1] + u[2] * v[2] + u[3] * v[3];
    }
    return s;
}

// ---------------------------------------------------------------------------
// K0b: precompB only. 403 blocks.
// ---------------------------------------------------------------------------
__global__ __launch_bounds__(256) void prep_scat(
    const float* __restrict__ Wpre_m, const float* __restrict__ Wpre_d,
    const float* __restrict__ Wpre_a, const float* __restrict__ bpre,
    const float* __restrict__ bq, const float* __restrict__ Wlin,
    const float* __restrict__ skip,
    char* __restrict__ ws)
{
    int tid = blockIdx.x * 256 + threadIdx.x;
    const float* WKA_D = (const float*)(ws + OFF_WKA_D);
    const float* WVM_D = (const float*)(ws + OFF_WVM_D);
    const float* WKA_A = (const float*)(ws + OFF_WKA_A);
    const float* WVM_A = (const float*)(ws + OFF_WVM_A);
    const float* WqT   = (const float*)(ws + OFF_WQT);

    if (tid < 36864) {
        int n = tid >> 8, c = tid & 255;
        float s = 0.0f;
        if (n < 128) {
            s = dot128(Wpre_m + c * 128, WqT + n * 128);
        } else if (n < 136) {
            int cc = n - 128;
            float g = 1.0f / (1.0f + __expf(-skip[0]));
            for (int e = 0; e < 128; e++)
                s += Wpre_m[c * 128 + e] * Wlin[e * 8 + cc];
            s *= (1.0f - g);
        }
        // HALF-MAJOR store: [c>>7][n][c&127]
        ((unsigned short*)(ws + OFF_BT_Q))[(c >> 7) * 18432 + n * 128 + (c & 127)] = f2bf(s);
    } else if (tid < 69632) {
        int idx = tid - 36864;
        int nrow = idx >> 7, c = idx & 127;
        const float* WfT = (nrow < 128) ? WKA_D : WVM_D;
        int nc = nrow & 127;
        float s = dot128(Wpre_d + c * 128, WfT + nc * 128);
        ((unsigned short*)(ws + OFF_BT_KAMV_D))[nrow * 128 + c] = f2bf(s);
    } else if (tid < 102400) {
        int idx = tid - 69632;
        int nrow = idx >> 7, c = idx & 127;
        const float* WfT = (nrow < 128) ? WKA_A : WVM_A;
        int nc = nrow & 127;
        float s = dot128(Wpre_a + c * 128, WfT + nc * 128);
        ((unsigned short*)(ws + OFF_BT_KAMV_A))[nrow * 128 + c] = f2bf(s);
    } else if (tid < 102544) {
        int n = tid - 102400;
        float s = 0.0f;
        if (n < 128) s = dot128(bpre, WqT + n * 128) + bq[n];
        ((float*)(ws + OFF_BQ))[n] = s;
    } else if (tid < 102800) {
        int nrow = tid - 102544;
        const float* WfT = (nrow < 128) ? WKA_D : WVM_D;
        const float* bf_ = (nrow < 128) ? (const float*)(ws + OFF_BKA_D) : (const float*)(ws + OFF_BVM_D);
        int nc = nrow & 127;
        ((float*)(ws + OFF_B_KAMV_D))[nrow] = dot128(bpre + 128, WfT + nc * 128) + bf_[nc];
    } else if (tid < 103056) {
        int nrow = tid - 102800;
        const float* WfT = (nrow < 128) ? WKA_A : WVM_A;
        const float* bf_ = (nrow < 128) ? (const float*)(ws + OFF_BKA_A) : (const float*)(ws + OFF_BVM_A);
        int nc = nrow & 127;
        ((float*)(ws + OFF_B_KAMV_A))[nrow] = dot128(bpre + 256, WfT + nc * 128) + bf_[nc];
    }
}

// ---------------------------------------------------------------------------
// gemm_all v2 + scatter interleaved into the tile loop.
// Each block handles 4 chunks of 256 edges, one per tile iteration (chunk
// id = i*GEMM_BLKS + bx, each chunk covered exactly once). The atomic+store
// chain overlaps the MFMA/epilogue phase instead of serializing as a prologue.
// ---------------------------------------------------------------------------
#define MFMA16(a, b, c) __builtin_amdgcn_mfma_f32_16x16x32_bf16(a, b, c, 0, 0, 0)

__global__ __launch_bounds__(256, 2) void gemm_all(
    const float* __restrict__ xm, const float* __restrict__ xd,
    const float* __restrict__ xa,
    const unsigned short* __restrict__ btq,   // [2][144][128] half-major
    const unsigned short* __restrict__ btd,   // [256][128]
    const unsigned short* __restrict__ bta,   // [256][128]
    const float* __restrict__ bq,
    const float* __restrict__ bbd, const float* __restrict__ bba,
    const int* __restrict__ src_dm, const int* __restrict__ dst_dm,
    const int* __restrict__ src_am, const int* __restrict__ dst_am,
    int* __restrict__ counts, int* __restrict__ slots,
    unsigned short* __restrict__ q0, float* __restrict__ skipb,
    unsigned short* __restrict__ outd, unsigned short* __restrict__ outa)
{
    __shared__ unsigned short b_lds[288 * 136];   // 78336 B (d/a use first 256 rows)
    int tid = threadIdx.x;
    int w = tid >> 6, lane = tid & 63;
    int quad = lane >> 4, low = lane & 15;
    int bx = blockIdx.x;

    if (bx < MB) {
        // ---------------- movie: q0 + skipb ----------------
        #pragma unroll
        for (int it = 0; it < 18; it++) {
            int idx = it * 256 + tid, r = idx >> 4, ch = idx & 15;
            *(intx4*)&b_lds[r * 136 + ch * 8] =
                *(const intx4*)&btq[(size_t)r * 128 + ch * 8];
        }
        __syncthreads();
        float bqr[9];
        #pragma unroll
        for (int j = 0; j < 9; j++) bqr[j] = bq[j * 16 + low];

        int t0 = (bx * 4 + w) * 4;
        floatx4 st[16];
        {   // stage first tile
            int te = t0 < NTM ? t0 : NTM - 1;
            const float* Ap = xm + (size_t)(te * 16 + low) * 256 + quad * 8;
            #pragma unroll
            for (int ks = 0; ks < 8; ks++) {
                st[2 * ks]     = *(const floatx4*)(Ap + ks * 32);
                st[2 * ks + 1] = *(const floatx4*)(Ap + ks * 32 + 4);
            }
        }
        #pragma unroll
        for (int i = 0; i < 4; i++) {
            int t = t0 + i;
            shortx8 fa[8];
            #pragma unroll
            for (int ks = 0; ks < 8; ks++) fa[ks] = pack8(st[2 * ks], st[2 * ks + 1]);
            {   // prefetch next tile (clamped; in flight during MFMAs)
                int tn = t + 1 < NTM ? t + 1 : NTM - 1;
                const float* Ap = xm + (size_t)(tn * 16 + low) * 256 + quad * 8;
                #pragma unroll
                for (int ks = 0; ks < 8; ks++) {
                    st[2 * ks]     = *(const floatx4*)(Ap + ks * 32);
                    st[2 * ks + 1] = *(const floatx4*)(Ap + ks * 32 + 4);
                }
            }
            // scatter chunk i (overlaps MFMA below)
            scat_one(((i * GEMM_BLKS + bx) << 8) + tid,
                     src_dm, dst_dm, src_am, dst_am, counts, slots);
            floatx4 acc[9] = {};
            #pragma unroll
            for (int ks = 0; ks < 8; ks++) {
                int rb = (ks >> 2) * 19584 + low * 136 + (ks & 3) * 32 + quad * 8;
                #pragma unroll
                for (int j = 0; j < 9; j++) {
                    shortx8 b = *(const shortx8*)&b_lds[rb + j * 2176];
                    acc[j] = MFMA16(fa[ks], b, acc[j]);
                }
            }
            if (t < NTM) {
                int row0 = t * 16 + quad * 4;
                #pragma unroll
                for (int j = 0; j < 8; j++) {
                    int col = j * 16 + low;
                    #pragma unroll
                    for (int r = 0; r < 4; r++)
                        q0[(size_t)(row0 + r) * 128 + col] = f2bf_fast(acc[j][r] + bqr[j]);
                }
                if (low < 8) {
                    #pragma unroll
                    for (int r = 0; r < 4; r++)
                        skipb[(size_t)(row0 + r) * 8 + low] = acc[8][r] + bqr[8];
                }
            }
        }
    } else {
        // ---------------- director / actor: ka|mv ----------------
        const float* A; const unsigned short* BT; const float* bias;
        unsigned short* outb; int ntt, wid;
        if (bx < MB + DB) { A = xd; BT = btd; bias = bbd; outb = outd; ntt = NTD; wid = (bx - MB) * 4 + w; }
        else              { A = xa; BT = bta; bias = bba; outb = outa; ntt = NTA; wid = (bx - MB - DB) * 4 + w; }
        #pragma unroll
        for (int it = 0; it < 16; it++) {
            int idx = it * 256 + tid, r = idx >> 4, ch = idx & 15;
            *(intx4*)&b_lds[r * 136 + ch * 8] =
                *(const intx4*)&BT[(size_t)r * 128 + ch * 8];
        }
        __syncthreads();
        float biasr[16];
        #pragma unroll
        for (int j = 0; j < 16; j++) biasr[j] = bias[j * 16 + low];

        int t0 = wid * 4;
        floatx4 st[8];
        {
            int te = t0 < ntt ? t0 : ntt - 1;
            const float* Ap = A + (size_t)(te * 16 + low) * 128 + quad * 8;
            #pragma unroll
            for (int ks = 0; ks < 4; ks++) {
                st[2 * ks]     = *(const floatx4*)(Ap + ks * 32);
                st[2 * ks + 1] = *(const floatx4*)(Ap + ks * 32 + 4);
            }
        }
        #pragma unroll
        for (int i = 0; i < 4; i++) {
            int t = t0 + i;
            shortx8 fa[4];
            #pragma unroll
            for (int ks = 0; ks < 4; ks++) fa[ks] = pack8(st[2 * ks], st[2 * ks + 1]);
            {
                int tn = t + 1 < ntt ? t + 1 : ntt - 1;
                const float* Ap = A + (size_t)(tn * 16 + low) * 128 + quad * 8;
                #pragma unroll
                for (int ks = 0; ks < 4; ks++) {
                    st[2 * ks]     = *(const floatx4*)(Ap + ks * 32);
                    st[2 * ks + 1] = *(const floatx4*)(Ap + ks * 32 + 4);
                }
            }
            // scatter chunk i (overlaps MFMA below)
            scat_one(((i * GEMM_BLKS + bx) << 8) + tid,
                     src_dm, dst_dm, src_am, dst_am, counts, slots);
            floatx4 acc[16] = {};
            #pragma unroll
            for (int ks = 0; ks < 4; ks++) {
                int rb = low * 136 + ks * 32 + quad * 8;
                #pragma unroll
                for (int j = 0; j < 16; j++) {
                    shortx8 b = *(const shortx8*)&b_lds[rb + j * 2176];
                    acc[j] = MFMA16(fa[ks], b, acc[j]);
                }
            }
            if (t < ntt) {
                int row0 = t * 16 + quad * 4;
                #pragma unroll
                for (int j = 0; j < 16; j++) {
                    int col = j * 16 + low;
                    #pragma unroll
                    for (int r = 0; r < 4; r++)
                        outb[(size_t)(row0 + r) * 256 + col] = f2bf_fast(acc[j][r] + biasr[j]);
                }
            }
        }
    }
}

// ---------------------------------------------------------------------------
// Aggregation: 16 lanes/node, 4 nodes/wave, 2-deep edge prefetch.
// ---------------------------------------------------------------------------
__global__ __launch_bounds__(256) void agg_kernel(
    const unsigned short* __restrict__ q0,
    const char* __restrict__ kamv0,      // = ws + OFF_KAMV_D
    const int* __restrict__ counts, const int* __restrict__ slots,
    const float* __restrict__ skipb,
    const float* __restrict__ WaLs, const float* __restrict__ bfin,
    float* __restrict__ out)
{
    __shared__ float wals[1032];   // [c][j*16+L] transposed-interleaved + bfin
    for (int i = threadIdx.x; i < 1024; i += 256) {
        int c = i >> 7, rem = i & 127, j = rem >> 4, L = rem & 15;
        wals[i] = WaLs[(L * 8 + j) * 8 + c];
    }
    if (threadIdx.x < 8) wals[1024 + threadIdx.x] = bfin[threadIdx.x];
    __syncthreads();

    int lane = threadIdx.x & 63;
    int grp = lane >> 4;
    int L   = lane & 15;
    int n = blockIdx.x * 16 + (threadIdx.x >> 6) * 4 + grp;

    intx4 qv = *(const intx4*)(q0 + (size_t)n * 128 + L * 8);
    float qf[8];
    #pragma unroll
    for (int d = 0; d < 4; d++) {
        unsigned int u = (unsigned int)qv[d];
        qf[2 * d]     = __uint_as_float(u << 16);
        qf[2 * d + 1] = __uint_as_float(u & 0xffff0000u);
    }

    int cnt = counts[n];
    cnt = cnt < 0 ? 0 : (cnt > CAP ? CAP : cnt);
    int s0 = slots[(size_t)n * CAP + L];

    float acc[8] = {0, 0, 0, 0, 0, 0, 0, 0};
    float den = 0.0f;
    if (cnt > 0) {
        // edge 0
        int off0 = __shfl(s0, lane & 48);
        const char* p0 = kamv0 + off0;
        intx4 ku = *(const intx4*)(p0 + L * 16);
        intx4 mu = *(const intx4*)(p0 + 256 + L * 16);
        // edge 1 (clamped)
        int e1 = 1 < cnt ? 1 : cnt - 1;
        int off1 = __shfl(s0, (lane & 48) + (e1 & 15));
        if (__builtin_expect(e1 >= 16, 0)) off1 = slots[(size_t)n * CAP + e1];
        const char* p1 = kamv0 + off1;
        intx4 kun = *(const intx4*)(p1 + L * 16);
        intx4 mun = *(const intx4*)(p1 + 256 + L * 16);

        for (int i = 0; i < cnt; i++) {
            // issue edge i+2 (clamped) -> consumed two iterations later
            int e2 = (i + 2 < cnt) ? i + 2 : cnt - 1;
            int off2 = __shfl(s0, (lane & 48) + (e2 & 15));
            if (__builtin_expect(e2 >= 16, 0)) off2 = slots[(size_t)n * CAP + e2];
            const char* p2 = kamv0 + off2;
            intx4 ku2 = *(const intx4*)(p2 + L * 16);
            intx4 mu2 = *(const intx4*)(p2 + 256 + L * 16);

            float ph = 0.0f;
            #pragma unroll
            for (int d = 0; d < 4; d++) {
                unsigned int u = (unsigned int)ku[d];
                ph += qf[2 * d]     * __uint_as_float(u << 16);
                ph += qf[2 * d + 1] * __uint_as_float(u & 0xffff0000u);
            }
            float pf = ph + __shfl_xor(ph, 1);
            float wgt = __expf(fminf(pf, 60.0f));
            den += wgt;
            #pragma unroll
            for (int d = 0; d < 4; d++) {
                unsigned int u = (unsigned int)mu[d];
                acc[2 * d]     += wgt * __uint_as_float(u << 16);
                acc[2 * d + 1] += wgt * __uint_as_float(u & 0xffff0000u);
            }
            ku = kun; mu = mun; kun = ku2; mun = mu2;
        }
    }
    float inv = 1.0f / fmaxf(den, 1e-16f);

    float part[8] = {0, 0, 0, 0, 0, 0, 0, 0};
    #pragma unroll
    for (int j = 0; j < 8; j++) {
        float u = gelu_exact(acc[j] * inv);
        #pragma unroll
        for (int c = 0; c < 8; c++)
            part[c] += u * wals[c * 128 + j * 16 + L];
    }

    bool b0 = lane & 1, b1 = lane & 2, b2 = lane & 4;
    float t1[4], t2[2], t3;
    #pragma unroll
    for (int k = 0; k < 4; k++) {
        float send = b0 ? part[k] : part[4 + k];
        float got  = __shfl_xor(send, 1);
        t1[k] = (b0 ? part[4 + k] : part[k]) + got;
    }
    #pragma unroll
    for (int k = 0; k < 2; k++) {
        float send = b1 ? t1[k] : t1[2 + k];
        float got  = __shfl_xor(send, 2);
        t2[k] = (b1 ? t1[2 + k] : t1[k]) + got;
    }
    {
        float send = b2 ? t2[0] : t2[1];
        float got  = __shfl_xor(send, 4);
        t3 = (b2 ? t2[1] : t2[0]) + got;
    }
    t3 += __shfl_xor(t3, 8);
    if (L < 8) {
        int c = 4 * (L & 1) + 2 * ((L >> 1) & 1) + ((L >> 2) & 1);
        out[(size_t)n * 8 + c] = t3 + skipb[(size_t)n * 8 + c] + wals[1024 + c];
    }
}

// ---------------------------------------------------------------------------
// Host launch — 4 dispatches (scatter interleaved inside gemm_all)
// ---------------------------------------------------------------------------
extern "C" void kernel_launch(void* const* d_in, const int* in_sizes, int n_in,
                              void* d_out, int out_size, void* d_ws, size_t ws_size,
                              hipStream_t stream) {
    (void)in_sizes; (void)n_in; (void)out_size; (void)ws_size;
    const float* x_movie    = (const float*)d_in[0];
    const float* x_director = (const float*)d_in[1];
    const float* x_actor    = (const float*)d_in[2];
    const int* src_dm = (const int*)d_in[3];
    const int* dst_dm = (const int*)d_in[4];
    const int* src_am = (const int*)d_in[5];
    const int* dst_am = (const int*)d_in[6];
    const float* Wpre_m = (const float*)d_in[11];
    const float* Wpre_d = (const float*)d_in[12];
    const float* Wpre_a = (const float*)d_in[13];
    const float* bpre   = (const float*)d_in[14];
    const float* Wk     = (const float*)d_in[15];
    const float* bk     = (const float*)d_in[16];
    const float* Wq     = (const float*)d_in[17];
    const float* bq     = (const float*)d_in[18];
    const float* Wv     = (const float*)d_in[19];
    const float* bv     = (const float*)d_in[20];
    const float* a_rel  = (const float*)d_in[21];
    const float* m_rel  = (const float*)d_in[22];
    const float* p_rel  = (const float*)d_in[23];
    const float* skip   = (const float*)d_in[24];
    const float* Wa     = (const float*)d_in[25];
    const float* ba     = (const float*)d_in[26];
    const float* Wlin   = (const float*)d_in[27];
    const float* blin   = (const float*)d_in[28];

    char* ws = (char*)d_ws;
    float* out = (float*)d_out;

    precompA<<<(83464 + NM + 255) / 256, 256, 0, stream>>>(
        Wk, bk, Wv, bv, Wa, ba, Wlin, blin,
        a_rel, m_rel, p_rel, skip, bpre, Wq, ws);

    prep_scat<<<403, 256, 0, stream>>>(
        Wpre_m, Wpre_d, Wpre_a, bpre, bq, Wlin, skip, ws);

    gemm_all<<<GEMM_BLKS, 256, 0, stream>>>(
        x_movie, x_director, x_actor,
        (const unsigned short*)(ws + OFF_BT_Q),
        (const unsigned short*)(ws + OFF_BT_KAMV_D),
        (const unsigned short*)(ws + OFF_BT_KAMV_A),
        (const float*)(ws + OFF_BQ),
        (const float*)(ws + OFF_B_KAMV_D), (const float*)(ws + OFF_B_KAMV_A),
        src_dm, dst_dm, src_am, dst_am,
        (int*)(ws + OFF_COUNTS), (int*)(ws + OFF_SLOTS),
        (unsigned short*)(ws + OFF_Q0), (float*)(ws + OFF_SKIPB),
        (unsigned short*)(ws + OFF_KAMV_D), (unsigned short*)(ws + OFF_KAMV_A));

    agg_kernel<<<NM / 16, 256, 0, stream>>>(
        (const unsigned short*)(ws + OFF_Q0),
        (const char*)(ws + OFF_KAMV_D),
        (const int*)(ws + OFF_COUNTS), (const int*)(ws + OFF_SLOTS),
        (const float*)(ws + OFF_SKIPB),
        (const float*)(ws + OFF_WALS), (const float*)(ws + OFF_BFIN), out);
}